// Round 12
// baseline (416.587 us; speedup 1.0000x reference)
//
#include <hip/hip_runtime.h>

// ---------------------------------------------------------------------------
// 2-layer GraphConv (DGL norm='both') + per-graph mean readout.
// R6-R11: kill ALL global atomics. R4/R6 counters: random-address device
// atomics run memory-side at ~23.5M/ms with ~31B HBM RMW each (k_count
// 51us/37MB). CSR build now: chunked LDS histogram (k_hist) -> partial
// reduce + exclusive split offsets (k_hreduce) -> scan -> rank-replay fill
// (k_fillr) writing fused 8B {src, weight} records. Zero global atomics in
// the whole pipeline (LDS atomics only). No memset needed.
// Pipeline:
//   1. k_hist:    dual LDS hist per (chunk,split) -> Pin/Pout partials
//   2. k_hreduce: cin + nin/nout; Pin -> exclusive per-split offsets
//   3. k_scan1/2/3: row offsets
//   4. k_fillr:   srw[pos] = {src, nout[src]*ew}, pos atomic-free
//   5. k_gemm<128>: t1 = x @ W1
//   6. k_agg<128,32>: h1 = leaky(nin * gather-sum(t1))
//   7. k_gemm<64>:  t2 = h1 @ W2
//   8. k_agg<64,16>: h2
//   9. k_rpart / k_rfinal: per-graph mean via LDS partials
// ---------------------------------------------------------------------------

#define LB256 __launch_bounds__(256)

constexpr int RB = 128;        // readout partial blocks
constexpr int CH = 8192;       // nodes per histogram chunk (32KB LDS per hist)
constexpr int CHB = 13;        // log2(CH)
constexpr int SPLIT = 16;      // edge slices per chunk

__device__ __forceinline__ float leaky(float v) { return v > 0.f ? v : 0.01f * v; }

// Dual LDS histogram: in-degree (dst) and out-degree (src) partials.
__global__ LB256 void k_hist(const int* __restrict__ src, const int* __restrict__ dst,
                             int* __restrict__ Pin, int* __restrict__ Pout,
                             int E, int epb) {
    __shared__ int hin[CH];
    __shared__ int hout[CH];
    const int c = blockIdx.x >> 4;       // SPLIT=16
    const int s = blockIdx.x & 15;
    const int t = threadIdx.x;
    for (int i = t; i < CH; i += 256) { hin[i] = 0; hout[i] = 0; }
    __syncthreads();

    const int base = c << CHB;
    const int e0 = s * epb, e1 = min(E, e0 + epb);
    for (int e = e0 + t; e < e1; e += 256) {
        const int dl = dst[e] - base;
        if ((unsigned)dl < (unsigned)CH) atomicAdd(&hin[dl], 1);
        const int sl = src[e] - base;
        if ((unsigned)sl < (unsigned)CH) atomicAdd(&hout[sl], 1);
    }
    __syncthreads();

    int* pi = &Pin[((size_t)c * SPLIT + s) * CH];
    int* po = &Pout[((size_t)c * SPLIT + s) * CH];
    for (int i = t; i < CH; i += 256) { pi[i] = hin[i]; po[i] = hout[i]; }
}

// Per node: cin = sum of Pin partials (converted in-place to exclusive
// per-split offsets), fused degree-norms.
__global__ LB256 void k_hreduce(int* __restrict__ Pin, const int* __restrict__ Pout,
                                int* __restrict__ cin, float* __restrict__ nin,
                                float* __restrict__ nout, int N) {
    const int i = blockIdx.x * 256 + threadIdx.x;
    if (i >= N) return;
    const int c = i >> CHB, l = i & (CH - 1);
    const size_t base = (size_t)c * SPLIT * CH + l;
    int acc = 0;
#pragma unroll
    for (int s = 0; s < SPLIT; ++s) {
        const size_t idx = base + (size_t)s * CH;
        const int v = Pin[idx];
        Pin[idx] = acc;          // exclusive offset of split s within row i
        acc += v;
    }
    int ao = 0;
#pragma unroll
    for (int s = 0; s < SPLIT; ++s) ao += Pout[base + (size_t)s * CH];
    cin[i] = acc;
    nin[i]  = rsqrtf(fmaxf((float)acc, 1.f));
    nout[i] = rsqrtf(fmaxf((float)ao, 1.f));
}

// inclusive block scan helper across 256 threads
__device__ __forceinline__ int block_scan_incl(int v, int t) {
    const int lane = t & 63, w = t >> 6;
#pragma unroll
    for (int off = 1; off < 64; off <<= 1) {
        int n = __shfl_up(v, off);
        if (lane >= off) v += n;
    }
    __shared__ int wsum[4];
    if (lane == 63) wsum[w] = v;
    __syncthreads();
    int base = 0;
#pragma unroll
    for (int k = 0; k < 4; ++k)
        if (k < w) base += wsum[k];
    return v + base;
}

__global__ LB256 void k_scan1(const int* __restrict__ cnt, int* __restrict__ excl,
                              int* __restrict__ bsum, int N) {
    const int t = threadIdx.x, i = blockIdx.x * 256 + t;
    const int orig = (i < N) ? cnt[i] : 0;
    const int incl = block_scan_incl(orig, t);
    if (i < N) excl[i] = incl - orig;
    if (t == 255) bsum[blockIdx.x] = incl;
}

__global__ LB256 void k_scan2(const int* __restrict__ bsum, int* __restrict__ boff, int NB) {
    const int t = threadIdx.x;
    const int orig = (t < NB) ? bsum[t] : 0;
    const int incl = block_scan_incl(orig, t);
    if (t < NB) boff[t] = incl - orig;
}

__global__ LB256 void k_scan3(const int* __restrict__ excl, const int* __restrict__ boff,
                              int* __restrict__ row_off, int N) {
    const int i = blockIdx.x * 256 + threadIdx.x;
    if (i < N) row_off[i] = excl[i] + boff[blockIdx.x];
}

// Rank-replay fill: same (chunk,split) decomposition as k_hist; LDS rank +
// precomputed split offset -> unique position, no global atomics.
__global__ LB256 void k_fillr(const int* __restrict__ src, const int* __restrict__ dst,
                              const float* __restrict__ ew, const float* __restrict__ nout,
                              const int* __restrict__ Pin, const int* __restrict__ row_off,
                              int2* __restrict__ srw, int E, int epb) {
    __shared__ int h[CH];
    const int c = blockIdx.x >> 4, s = blockIdx.x & 15, t = threadIdx.x;
    for (int i = t; i < CH; i += 256) h[i] = 0;
    __syncthreads();

    const int base = c << CHB;
    const int e0 = s * epb, e1 = min(E, e0 + epb);
    const int* off = &Pin[((size_t)c * SPLIT + s) * CH];
    for (int e = e0 + t; e < e1; e += 256) {
        const int d = dst[e];
        const int dl = d - base;
        if ((unsigned)dl < (unsigned)CH) {
            const int r = atomicAdd(&h[dl], 1);
            const int sv = src[e];
            const int pos = row_off[d] + off[dl] + r;
            srw[pos] = make_int2(sv, __float_as_int(nout[sv] * ew[e]));
        }
    }
}

// C[N][BN] = A[N][K] @ W[K][BN].  BM=64, BK=32, 256 thr as 16x16, 4xTN regs.
template <int BN, int TN>
__global__ LB256 void k_gemm(const float* __restrict__ A, const float* __restrict__ W,
                             float* __restrict__ C, int N, int K) {
    constexpr int BM = 64, BK = 32;
    __shared__ float Xs[BM][BK + 1];
    __shared__ float Ws[BK][BN];

    const int tid = threadIdx.x;
    const int r0 = blockIdx.x * BM;
    const int ty = tid >> 4;
    const int tx = tid & 15;

    float acc[4][TN];
#pragma unroll
    for (int i = 0; i < 4; ++i)
#pragma unroll
        for (int j = 0; j < TN; ++j) acc[i][j] = 0.f;

    const int lrow = tid >> 2;
    const int lc = (tid & 3) * 4;
    const int kr = tid >> 3;

    for (int kc = 0; kc < K; kc += BK) {
        const int gr = r0 + lrow;
        if (gr < N) {
            *(float4*)&Xs[lrow][lc]      = *(const float4*)&A[(size_t)gr * K + kc + lc];
            *(float4*)&Xs[lrow][lc + 16] = *(const float4*)&A[(size_t)gr * K + kc + lc + 16];
        } else {
            *(float4*)&Xs[lrow][lc]      = float4{0.f, 0.f, 0.f, 0.f};
            *(float4*)&Xs[lrow][lc + 16] = float4{0.f, 0.f, 0.f, 0.f};
        }
#pragma unroll
        for (int j = 0; j < BN / 32; ++j) {
            const int c4 = (tid & 7) + j * 8;
            *(float4*)&Ws[kr][c4 * 4] =
                *(const float4*)&W[(size_t)(kc + kr) * BN + c4 * 4];
        }
        __syncthreads();

#pragma unroll
        for (int k = 0; k < BK; ++k) {
            float xv[4];
#pragma unroll
            for (int i = 0; i < 4; ++i) xv[i] = Xs[ty * 4 + i][k];
            float wv[TN];
#pragma unroll
            for (int j4 = 0; j4 < TN / 4; ++j4) {
                const float4 w4 = *(const float4*)&Ws[k][tx * TN + j4 * 4];
                wv[j4 * 4 + 0] = w4.x; wv[j4 * 4 + 1] = w4.y;
                wv[j4 * 4 + 2] = w4.z; wv[j4 * 4 + 3] = w4.w;
            }
#pragma unroll
            for (int i = 0; i < 4; ++i)
#pragma unroll
                for (int j = 0; j < TN; ++j) acc[i][j] = fmaf(xv[i], wv[j], acc[i][j]);
        }
        __syncthreads();
    }

#pragma unroll
    for (int i = 0; i < 4; ++i) {
        const int r = r0 + ty * 4 + i;
        if (r < N) {
#pragma unroll
            for (int j4 = 0; j4 < TN / 4; ++j4) {
                float4 o{acc[i][j4 * 4 + 0], acc[i][j4 * 4 + 1],
                         acc[i][j4 * 4 + 2], acc[i][j4 * 4 + 3]};
                *(float4*)&C[(size_t)r * BN + tx * TN + j4 * 4] = o;
            }
        }
    }
}

// Pull-aggregate: one LANES-lane group per node, float4 per lane, 4-wide ILP.
// out[n] = leaky(nin[n] * sum_j w[j] * h[s[j]]), records srw = {s, w}.
template <int F, int LANES>
__global__ LB256 void k_agg(const int* __restrict__ row_off, const int* __restrict__ cnt,
                            const int2* __restrict__ srw, const float* __restrict__ nin,
                            const float* __restrict__ h, float* __restrict__ out, int N) {
    const int node = blockIdx.x * (256 / LANES) + threadIdx.x / LANES;
    if (node >= N) return;
    const int lane = threadIdx.x % LANES;
    const int start = row_off[node], len = cnt[node];

    float4 accA{0.f, 0.f, 0.f, 0.f}, accB{0.f, 0.f, 0.f, 0.f};
    int j = 0;
    for (; j + 3 < len; j += 4) {
        const int b = start + j;
        const int2 r0_ = srw[b + 0], r1_ = srw[b + 1], r2_ = srw[b + 2], r3_ = srw[b + 3];
        const float c0 = __int_as_float(r0_.y), c1 = __int_as_float(r1_.y);
        const float c2 = __int_as_float(r2_.y), c3 = __int_as_float(r3_.y);
        const float4 v0 = *(const float4*)&h[(size_t)r0_.x * F + lane * 4];
        const float4 v1 = *(const float4*)&h[(size_t)r1_.x * F + lane * 4];
        const float4 v2 = *(const float4*)&h[(size_t)r2_.x * F + lane * 4];
        const float4 v3 = *(const float4*)&h[(size_t)r3_.x * F + lane * 4];
        accA.x = fmaf(c0, v0.x, fmaf(c1, v1.x, accA.x));
        accA.y = fmaf(c0, v0.y, fmaf(c1, v1.y, accA.y));
        accA.z = fmaf(c0, v0.z, fmaf(c1, v1.z, accA.z));
        accA.w = fmaf(c0, v0.w, fmaf(c1, v1.w, accA.w));
        accB.x = fmaf(c2, v2.x, fmaf(c3, v3.x, accB.x));
        accB.y = fmaf(c2, v2.y, fmaf(c3, v3.y, accB.y));
        accB.z = fmaf(c2, v2.z, fmaf(c3, v3.z, accB.z));
        accB.w = fmaf(c2, v2.w, fmaf(c3, v3.w, accB.w));
    }
    for (; j < len; ++j) {
        const int2 r0_ = srw[start + j];
        const float c0 = __int_as_float(r0_.y);
        const float4 v0 = *(const float4*)&h[(size_t)r0_.x * F + lane * 4];
        accA.x = fmaf(c0, v0.x, accA.x);
        accA.y = fmaf(c0, v0.y, accA.y);
        accA.z = fmaf(c0, v0.z, accA.z);
        accA.w = fmaf(c0, v0.w, accA.w);
    }
    const float nd = nin[node];
    float4 o{leaky((accA.x + accB.x) * nd), leaky((accA.y + accB.y) * nd),
             leaky((accA.z + accB.z) * nd), leaky((accA.w + accB.w) * nd)};
    *(float4*)&out[(size_t)node * F + lane * 4] = o;
}

// Per-block LDS histogram over (graph, feat); coalesced partial dump.
__global__ LB256 void k_rpart(const float* __restrict__ h2, const int* __restrict__ gid,
                              float* __restrict__ part, int* __restrict__ pcnt,
                              int N, int npb) {
    __shared__ float lsum[128 * 64];
    __shared__ int lcnt[128];
    const int t = threadIdx.x;
    for (int i = t; i < 128 * 64; i += 256) lsum[i] = 0.f;
    if (t < 128) lcnt[t] = 0;
    __syncthreads();

    const int n0 = blockIdx.x * npb;
    const int n1 = min(N, n0 + npb);
    const int ty = t >> 6, lane = t & 63;
    for (int n = n0 + ty; n < n1; n += 4) {
        const int g = gid[n];
        atomicAdd(&lsum[g * 64 + lane], h2[(size_t)n * 64 + lane]);
        if (lane == 0) atomicAdd(&lcnt[g], 1);
    }
    __syncthreads();

    float* op = &part[(size_t)blockIdx.x * (128 * 64)];
    for (int i = t; i < 128 * 64; i += 256) op[i] = lsum[i];
    if (t < 128) pcnt[blockIdx.x * 128 + t] = lcnt[t];
}

__global__ LB256 void k_rfinal(const float* __restrict__ part, const int* __restrict__ pcnt,
                               float* __restrict__ out, int total) {
    const int i = blockIdx.x * 256 + threadIdx.x;
    if (i >= total) return;
    const int g = i >> 6;
    float s = 0.f;
    int c = 0;
#pragma unroll 4
    for (int b = 0; b < RB; ++b) {
        s += part[(size_t)b * (128 * 64) + i];
        c += pcnt[b * 128 + g];
    }
    out[i] = s / fmaxf((float)c, 1.f);
}

extern "C" void kernel_launch(void* const* d_in, const int* in_sizes, int n_in,
                              void* d_out, int out_size, void* d_ws, size_t ws_size,
                              hipStream_t stream) {
    const float* x   = (const float*)d_in[0];
    const float* ew  = (const float*)d_in[1];
    const float* W1  = (const float*)d_in[2];
    const float* W2  = (const float*)d_in[3];
    const int*   src = (const int*)d_in[4];
    const int*   dst = (const int*)d_in[5];
    const int*   gid = (const int*)d_in[6];

    const int N  = in_sizes[6];      // 50000
    const int E  = in_sizes[4];      // 600000
    const int NB = (N + 255) / 256;  // 196
    const int Na = (N + 63) & ~63;
    const int NCH = (N + CH - 1) / CH;          // 7 chunks
    const int epb = (E + SPLIT - 1) / SPLIT;    // edges per split

    // ---- workspace layout (no memset needed; everything fully written) ----
    char* p = (char*)d_ws;
    int*   cin     = (int*)p;                 p += (size_t)Na * 4;
    int*   excl    = (int*)p;                 p += (size_t)Na * 4;
    int*   bsum    = (int*)p;                 p += 256 * 4;
    int*   boff    = (int*)p;                 p += 256 * 4;
    int*   row_off = (int*)p;                 p += (size_t)Na * 4;
    float* nin     = (float*)p;               p += (size_t)Na * 4;
    float* nout    = (float*)p;               p += (size_t)Na * 4;
    int*   Pin     = (int*)p;                 p += (size_t)NCH * SPLIT * CH * 4;
    int*   Pout    = (int*)p;                 p += (size_t)NCH * SPLIT * CH * 4;
    int2*  srw     = (int2*)p;                p += (size_t)E * 8;
    float* t1      = (float*)p;               p += (size_t)N * 128 * 4;  // also t2
    float* h1      = (float*)p;               p += (size_t)N * 128 * 4;
    float* h2      = (float*)p;               p += (size_t)N * 64 * 4;
    float* part    = (float*)p;               p += (size_t)RB * 128 * 64 * 4;
    int*   pcnt    = (int*)p;                 /* RB*128 ints */

    k_hist<<<NCH * SPLIT, 256, 0, stream>>>(src, dst, Pin, Pout, E, epb);
    k_hreduce<<<NB, 256, 0, stream>>>(Pin, Pout, cin, nin, nout, N);
    k_scan1<<<NB, 256, 0, stream>>>(cin, excl, bsum, N);
    k_scan2<<<1, 256, 0, stream>>>(bsum, boff, NB);
    k_scan3<<<NB, 256, 0, stream>>>(excl, boff, row_off, N);
    k_fillr<<<NCH * SPLIT, 256, 0, stream>>>(src, dst, ew, nout, Pin, row_off,
                                             srw, E, epb);

    k_gemm<128, 8><<<(N + 63) / 64, 256, 0, stream>>>(x, W1, t1, N, 128);
    k_agg<128, 32><<<(N + 7) / 8, 256, 0, stream>>>(row_off, cin, srw, nin, t1, h1, N);

    k_gemm<64, 4><<<(N + 63) / 64, 256, 0, stream>>>(h1, W2, t1, N, 128);
    k_agg<64, 16><<<(N + 15) / 16, 256, 0, stream>>>(row_off, cin, srw, nin, t1, h2, N);

    const int npb = (N + RB - 1) / RB;
    k_rpart<<<RB, 256, 0, stream>>>(h2, gid, part, pcnt, N, npb);
    k_rfinal<<<(128 * 64 + 255) / 256, 256, 0, stream>>>(part, pcnt, (float*)d_out,
                                                         128 * 64);
}

// Round 13
// 279.243 us; speedup vs baseline: 1.4918x; 1.4918x over previous
//
#include <hip/hip_runtime.h>

// ---------------------------------------------------------------------------
// 2-layer GraphConv (DGL norm='both') + per-graph mean readout.
// R12: R12-bench exposed the atomic-free build's flaw: k_hist 128us @ 4.75%
// occupancy (grid 112, 1 wave/SIMD, scalar loads), k_fillr 100us. Fix: 512
// threads/block (8 waves/CU), SPLIT 16->32 (grid 224), int4/float4 edge
// loads (4 edges/thread/iter), int4 LDS zero/dump. Algorithm unchanged:
// zero global atomics (R6 counters: random-addr atomics ~23.5M/ms, 31B RMW).
// Pipeline:
//   1. k_hist:    dual LDS hist per (chunk,split) -> Pin/Pout partials
//   2. k_hreduce: cin + nin/nout; Pin -> exclusive per-split offsets
//   3. k_scan1/2/3: row offsets
//   4. k_fillr:   srw[pos] = {src, nout[src]*ew}, pos atomic-free
//   5. k_gemm<128>: t1 = x @ W1
//   6. k_agg<128,32>: h1 = leaky(nin * gather-sum(t1))
//   7. k_gemm<64>:  t2 = h1 @ W2
//   8. k_agg<64,16>: h2
//   9. k_rpart / k_rfinal: per-graph mean via LDS partials
// ---------------------------------------------------------------------------

#define LB256 __launch_bounds__(256)
#define LB512 __launch_bounds__(512)

constexpr int RB = 128;        // readout partial blocks
constexpr int CH = 8192;       // nodes per histogram chunk (32KB LDS per hist)
constexpr int CHB = 13;        // log2(CH)
constexpr int SPLIT = 32;      // edge slices per chunk (grid = NCH*SPLIT = 224)

__device__ __forceinline__ float leaky(float v) { return v > 0.f ? v : 0.01f * v; }

// Dual LDS histogram: in-degree (dst) and out-degree (src) partials.
// 512 threads, int4 edge loads. epb is a multiple of 4.
__global__ LB512 void k_hist(const int* __restrict__ src, const int* __restrict__ dst,
                             int* __restrict__ Pin, int* __restrict__ Pout,
                             int E, int epb) {
    __shared__ int hin[CH];
    __shared__ int hout[CH];
    const int c = blockIdx.x / SPLIT;
    const int s = blockIdx.x % SPLIT;
    const int t = threadIdx.x;
    const int4 z{0, 0, 0, 0};
    for (int i = t; i < CH / 4; i += 512) {
        ((int4*)hin)[i] = z;
        ((int4*)hout)[i] = z;
    }
    __syncthreads();

    const int base = c << CHB;
    const int e0 = s * epb;
    const int e1 = min(E, e0 + epb);
    if (e0 < e1) {
        const int nv = (e1 - e0) >> 2;  // int4 count
        const int4* d4 = (const int4*)(dst + e0);
        const int4* s4 = (const int4*)(src + e0);
        for (int i = t; i < nv; i += 512) {
            const int4 dd = d4[i], ss = s4[i];
            int v;
            v = dd.x - base; if ((unsigned)v < (unsigned)CH) atomicAdd(&hin[v], 1);
            v = dd.y - base; if ((unsigned)v < (unsigned)CH) atomicAdd(&hin[v], 1);
            v = dd.z - base; if ((unsigned)v < (unsigned)CH) atomicAdd(&hin[v], 1);
            v = dd.w - base; if ((unsigned)v < (unsigned)CH) atomicAdd(&hin[v], 1);
            v = ss.x - base; if ((unsigned)v < (unsigned)CH) atomicAdd(&hout[v], 1);
            v = ss.y - base; if ((unsigned)v < (unsigned)CH) atomicAdd(&hout[v], 1);
            v = ss.z - base; if ((unsigned)v < (unsigned)CH) atomicAdd(&hout[v], 1);
            v = ss.w - base; if ((unsigned)v < (unsigned)CH) atomicAdd(&hout[v], 1);
        }
        for (int e = e0 + (nv << 2) + t; e < e1; e += 512) {  // scalar tail
            int v = dst[e] - base; if ((unsigned)v < (unsigned)CH) atomicAdd(&hin[v], 1);
            v = src[e] - base;     if ((unsigned)v < (unsigned)CH) atomicAdd(&hout[v], 1);
        }
    }
    __syncthreads();

    int4* pi = (int4*)&Pin[((size_t)c * SPLIT + s) * CH];
    int4* po = (int4*)&Pout[((size_t)c * SPLIT + s) * CH];
    for (int i = t; i < CH / 4; i += 512) {
        pi[i] = ((const int4*)hin)[i];
        po[i] = ((const int4*)hout)[i];
    }
}

// Per node: cin = sum of Pin partials (converted in-place to exclusive
// per-split offsets), fused degree-norms.
__global__ LB256 void k_hreduce(int* __restrict__ Pin, const int* __restrict__ Pout,
                                int* __restrict__ cin, float* __restrict__ nin,
                                float* __restrict__ nout, int N) {
    const int i = blockIdx.x * 256 + threadIdx.x;
    if (i >= N) return;
    const int c = i >> CHB, l = i & (CH - 1);
    const size_t base = (size_t)c * SPLIT * CH + l;
    int acc = 0;
#pragma unroll
    for (int s = 0; s < SPLIT; ++s) {
        const size_t idx = base + (size_t)s * CH;
        const int v = Pin[idx];
        Pin[idx] = acc;          // exclusive offset of split s within row i
        acc += v;
    }
    int ao = 0;
#pragma unroll
    for (int s = 0; s < SPLIT; ++s) ao += Pout[base + (size_t)s * CH];
    cin[i] = acc;
    nin[i]  = rsqrtf(fmaxf((float)acc, 1.f));
    nout[i] = rsqrtf(fmaxf((float)ao, 1.f));
}

// inclusive block scan helper across 256 threads
__device__ __forceinline__ int block_scan_incl(int v, int t) {
    const int lane = t & 63, w = t >> 6;
#pragma unroll
    for (int off = 1; off < 64; off <<= 1) {
        int n = __shfl_up(v, off);
        if (lane >= off) v += n;
    }
    __shared__ int wsum[4];
    if (lane == 63) wsum[w] = v;
    __syncthreads();
    int base = 0;
#pragma unroll
    for (int k = 0; k < 4; ++k)
        if (k < w) base += wsum[k];
    return v + base;
}

__global__ LB256 void k_scan1(const int* __restrict__ cnt, int* __restrict__ excl,
                              int* __restrict__ bsum, int N) {
    const int t = threadIdx.x, i = blockIdx.x * 256 + t;
    const int orig = (i < N) ? cnt[i] : 0;
    const int incl = block_scan_incl(orig, t);
    if (i < N) excl[i] = incl - orig;
    if (t == 255) bsum[blockIdx.x] = incl;
}

__global__ LB256 void k_scan2(const int* __restrict__ bsum, int* __restrict__ boff, int NB) {
    const int t = threadIdx.x;
    const int orig = (t < NB) ? bsum[t] : 0;
    const int incl = block_scan_incl(orig, t);
    if (t < NB) boff[t] = incl - orig;
}

__global__ LB256 void k_scan3(const int* __restrict__ excl, const int* __restrict__ boff,
                              int* __restrict__ row_off, int N) {
    const int i = blockIdx.x * 256 + threadIdx.x;
    if (i < N) row_off[i] = excl[i] + boff[blockIdx.x];
}

// Rank-replay fill: same (chunk,split) decomposition as k_hist; LDS rank +
// precomputed split offset -> unique position, no global atomics.
// 512 threads, int4/float4 edge loads.
__global__ LB512 void k_fillr(const int* __restrict__ src, const int* __restrict__ dst,
                              const float* __restrict__ ew, const float* __restrict__ nout,
                              const int* __restrict__ Pin, const int* __restrict__ row_off,
                              int2* __restrict__ srw, int E, int epb) {
    __shared__ int h[CH];
    const int c = blockIdx.x / SPLIT;
    const int s = blockIdx.x % SPLIT;
    const int t = threadIdx.x;
    const int4 z{0, 0, 0, 0};
    for (int i = t; i < CH / 4; i += 512) ((int4*)h)[i] = z;
    __syncthreads();

    const int base = c << CHB;
    const int e0 = s * epb;
    const int e1 = min(E, e0 + epb);
    const int* off = &Pin[((size_t)c * SPLIT + s) * CH];
    if (e0 < e1) {
        const int nv = (e1 - e0) >> 2;
        const int4* d4 = (const int4*)(dst + e0);
        const int4* s4 = (const int4*)(src + e0);
        const float4* w4 = (const float4*)(ew + e0);
        for (int i = t; i < nv; i += 512) {
            const int4 dd = d4[i], ss = s4[i];
            const float4 ww = w4[i];
#define FILL1(D, S, W)                                                       \
            {                                                                \
                const int dl = (D) - base;                                   \
                if ((unsigned)dl < (unsigned)CH) {                           \
                    const int r = atomicAdd(&h[dl], 1);                      \
                    const int pos = row_off[D] + off[dl] + r;                \
                    srw[pos] = make_int2((S), __float_as_int(nout[S] * (W)));\
                }                                                            \
            }
            FILL1(dd.x, ss.x, ww.x)
            FILL1(dd.y, ss.y, ww.y)
            FILL1(dd.z, ss.z, ww.z)
            FILL1(dd.w, ss.w, ww.w)
        }
        for (int e = e0 + (nv << 2) + t; e < e1; e += 512) {  // scalar tail
            FILL1(dst[e], src[e], ew[e])
        }
#undef FILL1
    }
}

// C[N][BN] = A[N][K] @ W[K][BN].  BM=64, BK=32, 256 thr as 16x16, 4xTN regs.
template <int BN, int TN>
__global__ LB256 void k_gemm(const float* __restrict__ A, const float* __restrict__ W,
                             float* __restrict__ C, int N, int K) {
    constexpr int BM = 64, BK = 32;
    __shared__ float Xs[BM][BK + 1];
    __shared__ float Ws[BK][BN];

    const int tid = threadIdx.x;
    const int r0 = blockIdx.x * BM;
    const int ty = tid >> 4;
    const int tx = tid & 15;

    float acc[4][TN];
#pragma unroll
    for (int i = 0; i < 4; ++i)
#pragma unroll
        for (int j = 0; j < TN; ++j) acc[i][j] = 0.f;

    const int lrow = tid >> 2;
    const int lc = (tid & 3) * 4;
    const int kr = tid >> 3;

    for (int kc = 0; kc < K; kc += BK) {
        const int gr = r0 + lrow;
        if (gr < N) {
            *(float4*)&Xs[lrow][lc]      = *(const float4*)&A[(size_t)gr * K + kc + lc];
            *(float4*)&Xs[lrow][lc + 16] = *(const float4*)&A[(size_t)gr * K + kc + lc + 16];
        } else {
            *(float4*)&Xs[lrow][lc]      = float4{0.f, 0.f, 0.f, 0.f};
            *(float4*)&Xs[lrow][lc + 16] = float4{0.f, 0.f, 0.f, 0.f};
        }
#pragma unroll
        for (int j = 0; j < BN / 32; ++j) {
            const int c4 = (tid & 7) + j * 8;
            *(float4*)&Ws[kr][c4 * 4] =
                *(const float4*)&W[(size_t)(kc + kr) * BN + c4 * 4];
        }
        __syncthreads();

#pragma unroll
        for (int k = 0; k < BK; ++k) {
            float xv[4];
#pragma unroll
            for (int i = 0; i < 4; ++i) xv[i] = Xs[ty * 4 + i][k];
            float wv[TN];
#pragma unroll
            for (int j4 = 0; j4 < TN / 4; ++j4) {
                const float4 w4 = *(const float4*)&Ws[k][tx * TN + j4 * 4];
                wv[j4 * 4 + 0] = w4.x; wv[j4 * 4 + 1] = w4.y;
                wv[j4 * 4 + 2] = w4.z; wv[j4 * 4 + 3] = w4.w;
            }
#pragma unroll
            for (int i = 0; i < 4; ++i)
#pragma unroll
                for (int j = 0; j < TN; ++j) acc[i][j] = fmaf(xv[i], wv[j], acc[i][j]);
        }
        __syncthreads();
    }

#pragma unroll
    for (int i = 0; i < 4; ++i) {
        const int r = r0 + ty * 4 + i;
        if (r < N) {
#pragma unroll
            for (int j4 = 0; j4 < TN / 4; ++j4) {
                float4 o{acc[i][j4 * 4 + 0], acc[i][j4 * 4 + 1],
                         acc[i][j4 * 4 + 2], acc[i][j4 * 4 + 3]};
                *(float4*)&C[(size_t)r * BN + tx * TN + j4 * 4] = o;
            }
        }
    }
}

// Pull-aggregate: one LANES-lane group per node, float4 per lane, 4-wide ILP.
// out[n] = leaky(nin[n] * sum_j w[j] * h[s[j]]), records srw = {s, w}.
template <int F, int LANES>
__global__ LB256 void k_agg(const int* __restrict__ row_off, const int* __restrict__ cnt,
                            const int2* __restrict__ srw, const float* __restrict__ nin,
                            const float* __restrict__ h, float* __restrict__ out, int N) {
    const int node = blockIdx.x * (256 / LANES) + threadIdx.x / LANES;
    if (node >= N) return;
    const int lane = threadIdx.x % LANES;
    const int start = row_off[node], len = cnt[node];

    float4 accA{0.f, 0.f, 0.f, 0.f}, accB{0.f, 0.f, 0.f, 0.f};
    int j = 0;
    for (; j + 3 < len; j += 4) {
        const int b = start + j;
        const int2 r0_ = srw[b + 0], r1_ = srw[b + 1], r2_ = srw[b + 2], r3_ = srw[b + 3];
        const float c0 = __int_as_float(r0_.y), c1 = __int_as_float(r1_.y);
        const float c2 = __int_as_float(r2_.y), c3 = __int_as_float(r3_.y);
        const float4 v0 = *(const float4*)&h[(size_t)r0_.x * F + lane * 4];
        const float4 v1 = *(const float4*)&h[(size_t)r1_.x * F + lane * 4];
        const float4 v2 = *(const float4*)&h[(size_t)r2_.x * F + lane * 4];
        const float4 v3 = *(const float4*)&h[(size_t)r3_.x * F + lane * 4];
        accA.x = fmaf(c0, v0.x, fmaf(c1, v1.x, accA.x));
        accA.y = fmaf(c0, v0.y, fmaf(c1, v1.y, accA.y));
        accA.z = fmaf(c0, v0.z, fmaf(c1, v1.z, accA.z));
        accA.w = fmaf(c0, v0.w, fmaf(c1, v1.w, accA.w));
        accB.x = fmaf(c2, v2.x, fmaf(c3, v3.x, accB.x));
        accB.y = fmaf(c2, v2.y, fmaf(c3, v3.y, accB.y));
        accB.z = fmaf(c2, v2.z, fmaf(c3, v3.z, accB.z));
        accB.w = fmaf(c2, v2.w, fmaf(c3, v3.w, accB.w));
    }
    for (; j < len; ++j) {
        const int2 r0_ = srw[start + j];
        const float c0 = __int_as_float(r0_.y);
        const float4 v0 = *(const float4*)&h[(size_t)r0_.x * F + lane * 4];
        accA.x = fmaf(c0, v0.x, accA.x);
        accA.y = fmaf(c0, v0.y, accA.y);
        accA.z = fmaf(c0, v0.z, accA.z);
        accA.w = fmaf(c0, v0.w, accA.w);
    }
    const float nd = nin[node];
    float4 o{leaky((accA.x + accB.x) * nd), leaky((accA.y + accB.y) * nd),
             leaky((accA.z + accB.z) * nd), leaky((accA.w + accB.w) * nd)};
    *(float4*)&out[(size_t)node * F + lane * 4] = o;
}

// Per-block LDS histogram over (graph, feat); coalesced partial dump.
__global__ LB256 void k_rpart(const float* __restrict__ h2, const int* __restrict__ gid,
                              float* __restrict__ part, int* __restrict__ pcnt,
                              int N, int npb) {
    __shared__ float lsum[128 * 64];
    __shared__ int lcnt[128];
    const int t = threadIdx.x;
    for (int i = t; i < 128 * 64; i += 256) lsum[i] = 0.f;
    if (t < 128) lcnt[t] = 0;
    __syncthreads();

    const int n0 = blockIdx.x * npb;
    const int n1 = min(N, n0 + npb);
    const int ty = t >> 6, lane = t & 63;
    for (int n = n0 + ty; n < n1; n += 4) {
        const int g = gid[n];
        atomicAdd(&lsum[g * 64 + lane], h2[(size_t)n * 64 + lane]);
        if (lane == 0) atomicAdd(&lcnt[g], 1);
    }
    __syncthreads();

    float* op = &part[(size_t)blockIdx.x * (128 * 64)];
    for (int i = t; i < 128 * 64; i += 256) op[i] = lsum[i];
    if (t < 128) pcnt[blockIdx.x * 128 + t] = lcnt[t];
}

__global__ LB256 void k_rfinal(const float* __restrict__ part, const int* __restrict__ pcnt,
                               float* __restrict__ out, int total) {
    const int i = blockIdx.x * 256 + threadIdx.x;
    if (i >= total) return;
    const int g = i >> 6;
    float s = 0.f;
    int c = 0;
#pragma unroll 4
    for (int b = 0; b < RB; ++b) {
        s += part[(size_t)b * (128 * 64) + i];
        c += pcnt[b * 128 + g];
    }
    out[i] = s / fmaxf((float)c, 1.f);
}

extern "C" void kernel_launch(void* const* d_in, const int* in_sizes, int n_in,
                              void* d_out, int out_size, void* d_ws, size_t ws_size,
                              hipStream_t stream) {
    const float* x   = (const float*)d_in[0];
    const float* ew  = (const float*)d_in[1];
    const float* W1  = (const float*)d_in[2];
    const float* W2  = (const float*)d_in[3];
    const int*   src = (const int*)d_in[4];
    const int*   dst = (const int*)d_in[5];
    const int*   gid = (const int*)d_in[6];

    const int N  = in_sizes[6];      // 50000
    const int E  = in_sizes[4];      // 600000
    const int NB = (N + 255) / 256;  // 196
    const int Na = (N + 63) & ~63;
    const int NCH = (N + CH - 1) / CH;                       // 7 chunks
    const int epb = (((E + SPLIT - 1) / SPLIT) + 3) & ~3;    // mult-of-4 slice

    // ---- workspace layout (no memset needed; everything fully written) ----
    char* p = (char*)d_ws;
    int*   cin     = (int*)p;                 p += (size_t)Na * 4;
    int*   excl    = (int*)p;                 p += (size_t)Na * 4;
    int*   bsum    = (int*)p;                 p += 256 * 4;
    int*   boff    = (int*)p;                 p += 256 * 4;
    int*   row_off = (int*)p;                 p += (size_t)Na * 4;
    float* nin     = (float*)p;               p += (size_t)Na * 4;
    float* nout    = (float*)p;               p += (size_t)Na * 4;
    int*   Pin     = (int*)p;                 p += (size_t)NCH * SPLIT * CH * 4;
    int*   Pout    = (int*)p;                 p += (size_t)NCH * SPLIT * CH * 4;
    int2*  srw     = (int2*)p;                p += (size_t)E * 8;
    float* t1      = (float*)p;               p += (size_t)N * 128 * 4;  // also t2
    float* h1      = (float*)p;               p += (size_t)N * 128 * 4;
    float* h2      = (float*)p;               p += (size_t)N * 64 * 4;
    float* part    = (float*)p;               p += (size_t)RB * 128 * 64 * 4;
    int*   pcnt    = (int*)p;                 /* RB*128 ints */

    k_hist<<<NCH * SPLIT, 512, 0, stream>>>(src, dst, Pin, Pout, E, epb);
    k_hreduce<<<NB, 256, 0, stream>>>(Pin, Pout, cin, nin, nout, N);
    k_scan1<<<NB, 256, 0, stream>>>(cin, excl, bsum, N);
    k_scan2<<<1, 256, 0, stream>>>(bsum, boff, NB);
    k_scan3<<<NB, 256, 0, stream>>>(excl, boff, row_off, N);
    k_fillr<<<NCH * SPLIT, 512, 0, stream>>>(src, dst, ew, nout, Pin, row_off,
                                             srw, E, epb);

    k_gemm<128, 8><<<(N + 63) / 64, 256, 0, stream>>>(x, W1, t1, N, 128);
    k_agg<128, 32><<<(N + 7) / 8, 256, 0, stream>>>(row_off, cin, srw, nin, t1, h1, N);

    k_gemm<64, 4><<<(N + 63) / 64, 256, 0, stream>>>(h1, W2, t1, N, 128);
    k_agg<64, 16><<<(N + 15) / 16, 256, 0, stream>>>(row_off, cin, srw, nin, t1, h2, N);

    const int npb = (N + RB - 1) / RB;
    k_rpart<<<RB, 256, 0, stream>>>(h2, gid, part, pcnt, N, npb);
    k_rfinal<<<(128 * 64 + 255) / 256, 256, 0, stream>>>(part, pcnt, (float*)d_out,
                                                         128 * 64);
}

// Round 14
// 274.654 us; speedup vs baseline: 1.5168x; 1.0167x over previous
//
#include <hip/hip_runtime.h>

// ---------------------------------------------------------------------------
// 2-layer GraphConv (DGL norm='both') + per-graph mean readout.
// R13: R13-bench: k_agg<128,32> now top at 43.4us, HBM counter 47%, VALU 13%,
// occ 66% -- random-gather regime. Levers: 6-wide gather unroll w/ 3 accs
// (<64 VGPR, keeps 8 waves/SIMD), fuse hreduce+scan1, RB 128->256.
// Build phase unchanged (R12 fix: 512thr, SPLIT=32, int4 loads; zero global
// atomics per R6 evidence: random-addr atomics ~23.5M/ms, 31B RMW each).
// Pipeline:
//   1. k_hist:      dual LDS hist per (chunk,split) -> Pin/Pout partials
//   2. k_hredscan:  cin + nin/nout + per-split offsets + block scan (fused)
//   3. k_scan2/3:   row offsets
//   4. k_fillr:     srw[pos] = {src, nout[src]*ew}, pos atomic-free
//   5. k_gemm<128>: t1 = x @ W1
//   6. k_agg<128,32>: h1 = leaky(nin * gather-sum(t1))
//   7. k_gemm<64>:  t2 = h1 @ W2
//   8. k_agg<64,16>: h2
//   9. k_rpart / k_rfinal: per-graph mean via LDS partials
// ---------------------------------------------------------------------------

#define LB256 __launch_bounds__(256)
#define LB512 __launch_bounds__(512)

constexpr int RB = 256;        // readout partial blocks (full-chip)
constexpr int CH = 8192;       // nodes per histogram chunk (32KB LDS per hist)
constexpr int CHB = 13;        // log2(CH)
constexpr int SPLIT = 32;      // edge slices per chunk (grid = NCH*SPLIT = 224)

__device__ __forceinline__ float leaky(float v) { return v > 0.f ? v : 0.01f * v; }

// Dual LDS histogram: in-degree (dst) and out-degree (src) partials.
// 512 threads, int4 edge loads. epb is a multiple of 4.
__global__ LB512 void k_hist(const int* __restrict__ src, const int* __restrict__ dst,
                             int* __restrict__ Pin, int* __restrict__ Pout,
                             int E, int epb) {
    __shared__ int hin[CH];
    __shared__ int hout[CH];
    const int c = blockIdx.x / SPLIT;
    const int s = blockIdx.x % SPLIT;
    const int t = threadIdx.x;
    const int4 z{0, 0, 0, 0};
    for (int i = t; i < CH / 4; i += 512) {
        ((int4*)hin)[i] = z;
        ((int4*)hout)[i] = z;
    }
    __syncthreads();

    const int base = c << CHB;
    const int e0 = s * epb;
    const int e1 = min(E, e0 + epb);
    if (e0 < e1) {
        const int nv = (e1 - e0) >> 2;  // int4 count
        const int4* d4 = (const int4*)(dst + e0);
        const int4* s4 = (const int4*)(src + e0);
        for (int i = t; i < nv; i += 512) {
            const int4 dd = d4[i], ss = s4[i];
            int v;
            v = dd.x - base; if ((unsigned)v < (unsigned)CH) atomicAdd(&hin[v], 1);
            v = dd.y - base; if ((unsigned)v < (unsigned)CH) atomicAdd(&hin[v], 1);
            v = dd.z - base; if ((unsigned)v < (unsigned)CH) atomicAdd(&hin[v], 1);
            v = dd.w - base; if ((unsigned)v < (unsigned)CH) atomicAdd(&hin[v], 1);
            v = ss.x - base; if ((unsigned)v < (unsigned)CH) atomicAdd(&hout[v], 1);
            v = ss.y - base; if ((unsigned)v < (unsigned)CH) atomicAdd(&hout[v], 1);
            v = ss.z - base; if ((unsigned)v < (unsigned)CH) atomicAdd(&hout[v], 1);
            v = ss.w - base; if ((unsigned)v < (unsigned)CH) atomicAdd(&hout[v], 1);
        }
        for (int e = e0 + (nv << 2) + t; e < e1; e += 512) {  // scalar tail
            int v = dst[e] - base; if ((unsigned)v < (unsigned)CH) atomicAdd(&hin[v], 1);
            v = src[e] - base;     if ((unsigned)v < (unsigned)CH) atomicAdd(&hout[v], 1);
        }
    }
    __syncthreads();

    int4* pi = (int4*)&Pin[((size_t)c * SPLIT + s) * CH];
    int4* po = (int4*)&Pout[((size_t)c * SPLIT + s) * CH];
    for (int i = t; i < CH / 4; i += 512) {
        pi[i] = ((const int4*)hin)[i];
        po[i] = ((const int4*)hout)[i];
    }
}

// inclusive block scan helper across 256 threads
__device__ __forceinline__ int block_scan_incl(int v, int t) {
    const int lane = t & 63, w = t >> 6;
#pragma unroll
    for (int off = 1; off < 64; off <<= 1) {
        int n = __shfl_up(v, off);
        if (lane >= off) v += n;
    }
    __shared__ int wsum[4];
    if (lane == 63) wsum[w] = v;
    __syncthreads();
    int base = 0;
#pragma unroll
    for (int k = 0; k < 4; ++k)
        if (k < w) base += wsum[k];
    return v + base;
}

// Fused: per-node reduce of Pin/Pout (Pin -> exclusive split offsets in
// place), degree norms, AND block-level inclusive scan of cin (R13 fusion --
// identical index geometry, saves a dispatch + cin re-read).
__global__ LB256 void k_hredscan(int* __restrict__ Pin, const int* __restrict__ Pout,
                                 int* __restrict__ cin, float* __restrict__ nin,
                                 float* __restrict__ nout, int* __restrict__ excl,
                                 int* __restrict__ bsum, int N) {
    const int t = threadIdx.x, i = blockIdx.x * 256 + t;
    int acc = 0;
    if (i < N) {
        const int c = i >> CHB, l = i & (CH - 1);
        const size_t base = (size_t)c * SPLIT * CH + l;
#pragma unroll
        for (int s = 0; s < SPLIT; ++s) {
            const size_t idx = base + (size_t)s * CH;
            const int v = Pin[idx];
            Pin[idx] = acc;          // exclusive offset of split s within row i
            acc += v;
        }
        int ao = 0;
#pragma unroll
        for (int s = 0; s < SPLIT; ++s) ao += Pout[base + (size_t)s * CH];
        cin[i] = acc;
        nin[i]  = rsqrtf(fmaxf((float)acc, 1.f));
        nout[i] = rsqrtf(fmaxf((float)ao, 1.f));
    }
    const int incl = block_scan_incl(acc, t);  // acc==0 for i>=N
    if (i < N) excl[i] = incl - acc;
    if (t == 255) bsum[blockIdx.x] = incl;
}

__global__ LB256 void k_scan2(const int* __restrict__ bsum, int* __restrict__ boff, int NB) {
    const int t = threadIdx.x;
    const int orig = (t < NB) ? bsum[t] : 0;
    const int incl = block_scan_incl(orig, t);
    if (t < NB) boff[t] = incl - orig;
}

__global__ LB256 void k_scan3(const int* __restrict__ excl, const int* __restrict__ boff,
                              int* __restrict__ row_off, int N) {
    const int i = blockIdx.x * 256 + threadIdx.x;
    if (i < N) row_off[i] = excl[i] + boff[blockIdx.x];
}

// Rank-replay fill: same (chunk,split) decomposition as k_hist; LDS rank +
// precomputed split offset -> unique position, no global atomics.
// 512 threads, int4/float4 edge loads.
__global__ LB512 void k_fillr(const int* __restrict__ src, const int* __restrict__ dst,
                              const float* __restrict__ ew, const float* __restrict__ nout,
                              const int* __restrict__ Pin, const int* __restrict__ row_off,
                              int2* __restrict__ srw, int E, int epb) {
    __shared__ int h[CH];
    const int c = blockIdx.x / SPLIT;
    const int s = blockIdx.x % SPLIT;
    const int t = threadIdx.x;
    const int4 z{0, 0, 0, 0};
    for (int i = t; i < CH / 4; i += 512) ((int4*)h)[i] = z;
    __syncthreads();

    const int base = c << CHB;
    const int e0 = s * epb;
    const int e1 = min(E, e0 + epb);
    const int* off = &Pin[((size_t)c * SPLIT + s) * CH];
    if (e0 < e1) {
        const int nv = (e1 - e0) >> 2;
        const int4* d4 = (const int4*)(dst + e0);
        const int4* s4 = (const int4*)(src + e0);
        const float4* w4 = (const float4*)(ew + e0);
        for (int i = t; i < nv; i += 512) {
            const int4 dd = d4[i], ss = s4[i];
            const float4 ww = w4[i];
#define FILL1(D, S, W)                                                       \
            {                                                                \
                const int dl = (D) - base;                                   \
                if ((unsigned)dl < (unsigned)CH) {                           \
                    const int r = atomicAdd(&h[dl], 1);                      \
                    const int pos = row_off[D] + off[dl] + r;                \
                    srw[pos] = make_int2((S), __float_as_int(nout[S] * (W)));\
                }                                                            \
            }
            FILL1(dd.x, ss.x, ww.x)
            FILL1(dd.y, ss.y, ww.y)
            FILL1(dd.z, ss.z, ww.z)
            FILL1(dd.w, ss.w, ww.w)
        }
        for (int e = e0 + (nv << 2) + t; e < e1; e += 512) {  // scalar tail
            FILL1(dst[e], src[e], ew[e])
        }
#undef FILL1
    }
}

// C[N][BN] = A[N][K] @ W[K][BN].  BM=64, BK=32, 256 thr as 16x16, 4xTN regs.
template <int BN, int TN>
__global__ LB256 void k_gemm(const float* __restrict__ A, const float* __restrict__ W,
                             float* __restrict__ C, int N, int K) {
    constexpr int BM = 64, BK = 32;
    __shared__ float Xs[BM][BK + 1];
    __shared__ float Ws[BK][BN];

    const int tid = threadIdx.x;
    const int r0 = blockIdx.x * BM;
    const int ty = tid >> 4;
    const int tx = tid & 15;

    float acc[4][TN];
#pragma unroll
    for (int i = 0; i < 4; ++i)
#pragma unroll
        for (int j = 0; j < TN; ++j) acc[i][j] = 0.f;

    const int lrow = tid >> 2;
    const int lc = (tid & 3) * 4;
    const int kr = tid >> 3;

    for (int kc = 0; kc < K; kc += BK) {
        const int gr = r0 + lrow;
        if (gr < N) {
            *(float4*)&Xs[lrow][lc]      = *(const float4*)&A[(size_t)gr * K + kc + lc];
            *(float4*)&Xs[lrow][lc + 16] = *(const float4*)&A[(size_t)gr * K + kc + lc + 16];
        } else {
            *(float4*)&Xs[lrow][lc]      = float4{0.f, 0.f, 0.f, 0.f};
            *(float4*)&Xs[lrow][lc + 16] = float4{0.f, 0.f, 0.f, 0.f};
        }
#pragma unroll
        for (int j = 0; j < BN / 32; ++j) {
            const int c4 = (tid & 7) + j * 8;
            *(float4*)&Ws[kr][c4 * 4] =
                *(const float4*)&W[(size_t)(kc + kr) * BN + c4 * 4];
        }
        __syncthreads();

#pragma unroll
        for (int k = 0; k < BK; ++k) {
            float xv[4];
#pragma unroll
            for (int i = 0; i < 4; ++i) xv[i] = Xs[ty * 4 + i][k];
            float wv[TN];
#pragma unroll
            for (int j4 = 0; j4 < TN / 4; ++j4) {
                const float4 w4 = *(const float4*)&Ws[k][tx * TN + j4 * 4];
                wv[j4 * 4 + 0] = w4.x; wv[j4 * 4 + 1] = w4.y;
                wv[j4 * 4 + 2] = w4.z; wv[j4 * 4 + 3] = w4.w;
            }
#pragma unroll
            for (int i = 0; i < 4; ++i)
#pragma unroll
                for (int j = 0; j < TN; ++j) acc[i][j] = fmaf(xv[i], wv[j], acc[i][j]);
        }
        __syncthreads();
    }

#pragma unroll
    for (int i = 0; i < 4; ++i) {
        const int r = r0 + ty * 4 + i;
        if (r < N) {
#pragma unroll
            for (int j4 = 0; j4 < TN / 4; ++j4) {
                float4 o{acc[i][j4 * 4 + 0], acc[i][j4 * 4 + 1],
                         acc[i][j4 * 4 + 2], acc[i][j4 * 4 + 3]};
                *(float4*)&C[(size_t)r * BN + tx * TN + j4 * 4] = o;
            }
        }
    }
}

// Pull-aggregate: one LANES-lane group per node, float4 per lane.
// R13: 6-wide unroll, 3 independent accumulators (more loads in flight;
// est <64 VGPR so 8 waves/SIMD retained).
// out[n] = leaky(nin[n] * sum_j w[j] * h[s[j]]), records srw = {s, w}.
template <int F, int LANES>
__global__ LB256 void k_agg(const int* __restrict__ row_off, const int* __restrict__ cnt,
                            const int2* __restrict__ srw, const float* __restrict__ nin,
                            const float* __restrict__ h, float* __restrict__ out, int N) {
    const int node = blockIdx.x * (256 / LANES) + threadIdx.x / LANES;
    if (node >= N) return;
    const int lane = threadIdx.x % LANES;
    const int start = row_off[node], len = cnt[node];

    float4 a0{0.f, 0.f, 0.f, 0.f}, a1{0.f, 0.f, 0.f, 0.f}, a2{0.f, 0.f, 0.f, 0.f};
    int j = 0;
    for (; j + 5 < len; j += 6) {
        const int b = start + j;
        const int2 rr0 = srw[b + 0], rr1 = srw[b + 1], rr2 = srw[b + 2];
        const int2 rr3 = srw[b + 3], rr4 = srw[b + 4], rr5 = srw[b + 5];
        const float4 v0 = *(const float4*)&h[(size_t)rr0.x * F + lane * 4];
        const float4 v1 = *(const float4*)&h[(size_t)rr1.x * F + lane * 4];
        const float4 v2 = *(const float4*)&h[(size_t)rr2.x * F + lane * 4];
        const float4 v3 = *(const float4*)&h[(size_t)rr3.x * F + lane * 4];
        const float4 v4 = *(const float4*)&h[(size_t)rr4.x * F + lane * 4];
        const float4 v5 = *(const float4*)&h[(size_t)rr5.x * F + lane * 4];
        const float c0 = __int_as_float(rr0.y), c1 = __int_as_float(rr1.y);
        const float c2 = __int_as_float(rr2.y), c3 = __int_as_float(rr3.y);
        const float c4 = __int_as_float(rr4.y), c5 = __int_as_float(rr5.y);
        a0.x = fmaf(c0, v0.x, fmaf(c1, v1.x, a0.x));
        a0.y = fmaf(c0, v0.y, fmaf(c1, v1.y, a0.y));
        a0.z = fmaf(c0, v0.z, fmaf(c1, v1.z, a0.z));
        a0.w = fmaf(c0, v0.w, fmaf(c1, v1.w, a0.w));
        a1.x = fmaf(c2, v2.x, fmaf(c3, v3.x, a1.x));
        a1.y = fmaf(c2, v2.y, fmaf(c3, v3.y, a1.y));
        a1.z = fmaf(c2, v2.z, fmaf(c3, v3.z, a1.z));
        a1.w = fmaf(c2, v2.w, fmaf(c3, v3.w, a1.w));
        a2.x = fmaf(c4, v4.x, fmaf(c5, v5.x, a2.x));
        a2.y = fmaf(c4, v4.y, fmaf(c5, v5.y, a2.y));
        a2.z = fmaf(c4, v4.z, fmaf(c5, v5.z, a2.z));
        a2.w = fmaf(c4, v4.w, fmaf(c5, v5.w, a2.w));
    }
    for (; j + 1 < len; j += 2) {
        const int b = start + j;
        const int2 rr0 = srw[b + 0], rr1 = srw[b + 1];
        const float4 v0 = *(const float4*)&h[(size_t)rr0.x * F + lane * 4];
        const float4 v1 = *(const float4*)&h[(size_t)rr1.x * F + lane * 4];
        const float c0 = __int_as_float(rr0.y), c1 = __int_as_float(rr1.y);
        a0.x = fmaf(c0, v0.x, fmaf(c1, v1.x, a0.x));
        a0.y = fmaf(c0, v0.y, fmaf(c1, v1.y, a0.y));
        a0.z = fmaf(c0, v0.z, fmaf(c1, v1.z, a0.z));
        a0.w = fmaf(c0, v0.w, fmaf(c1, v1.w, a0.w));
    }
    if (j < len) {
        const int2 rr0 = srw[start + j];
        const float c0 = __int_as_float(rr0.y);
        const float4 v0 = *(const float4*)&h[(size_t)rr0.x * F + lane * 4];
        a0.x = fmaf(c0, v0.x, a0.x);
        a0.y = fmaf(c0, v0.y, a0.y);
        a0.z = fmaf(c0, v0.z, a0.z);
        a0.w = fmaf(c0, v0.w, a0.w);
    }
    const float nd = nin[node];
    float4 o{leaky((a0.x + a1.x + a2.x) * nd), leaky((a0.y + a1.y + a2.y) * nd),
             leaky((a0.z + a1.z + a2.z) * nd), leaky((a0.w + a1.w + a2.w) * nd)};
    *(float4*)&out[(size_t)node * F + lane * 4] = o;
}

// Per-block LDS histogram over (graph, feat); coalesced partial dump.
__global__ LB256 void k_rpart(const float* __restrict__ h2, const int* __restrict__ gid,
                              float* __restrict__ part, int* __restrict__ pcnt,
                              int N, int npb) {
    __shared__ float lsum[128 * 64];
    __shared__ int lcnt[128];
    const int t = threadIdx.x;
    for (int i = t; i < 128 * 64; i += 256) lsum[i] = 0.f;
    if (t < 128) lcnt[t] = 0;
    __syncthreads();

    const int n0 = blockIdx.x * npb;
    const int n1 = min(N, n0 + npb);
    const int ty = t >> 6, lane = t & 63;
    for (int n = n0 + ty; n < n1; n += 4) {
        const int g = gid[n];
        atomicAdd(&lsum[g * 64 + lane], h2[(size_t)n * 64 + lane]);
        if (lane == 0) atomicAdd(&lcnt[g], 1);
    }
    __syncthreads();

    float* op = &part[(size_t)blockIdx.x * (128 * 64)];
    for (int i = t; i < 128 * 64; i += 256) op[i] = lsum[i];
    if (t < 128) pcnt[blockIdx.x * 128 + t] = lcnt[t];
}

__global__ LB256 void k_rfinal(const float* __restrict__ part, const int* __restrict__ pcnt,
                               float* __restrict__ out, int total) {
    const int i = blockIdx.x * 256 + threadIdx.x;
    if (i >= total) return;
    const int g = i >> 6;
    float s = 0.f;
    int c = 0;
#pragma unroll 4
    for (int b = 0; b < RB; ++b) {
        s += part[(size_t)b * (128 * 64) + i];
        c += pcnt[b * 128 + g];
    }
    out[i] = s / fmaxf((float)c, 1.f);
}

extern "C" void kernel_launch(void* const* d_in, const int* in_sizes, int n_in,
                              void* d_out, int out_size, void* d_ws, size_t ws_size,
                              hipStream_t stream) {
    const float* x   = (const float*)d_in[0];
    const float* ew  = (const float*)d_in[1];
    const float* W1  = (const float*)d_in[2];
    const float* W2  = (const float*)d_in[3];
    const int*   src = (const int*)d_in[4];
    const int*   dst = (const int*)d_in[5];
    const int*   gid = (const int*)d_in[6];

    const int N  = in_sizes[6];      // 50000
    const int E  = in_sizes[4];      // 600000
    const int NB = (N + 255) / 256;  // 196
    const int Na = (N + 63) & ~63;
    const int NCH = (N + CH - 1) / CH;                       // 7 chunks
    const int epb = (((E + SPLIT - 1) / SPLIT) + 3) & ~3;    // mult-of-4 slice

    // ---- workspace layout (no memset needed; everything fully written) ----
    char* p = (char*)d_ws;
    int*   cin     = (int*)p;                 p += (size_t)Na * 4;
    int*   excl    = (int*)p;                 p += (size_t)Na * 4;
    int*   bsum    = (int*)p;                 p += 256 * 4;
    int*   boff    = (int*)p;                 p += 256 * 4;
    int*   row_off = (int*)p;                 p += (size_t)Na * 4;
    float* nin     = (float*)p;               p += (size_t)Na * 4;
    float* nout    = (float*)p;               p += (size_t)Na * 4;
    int*   Pin     = (int*)p;                 p += (size_t)NCH * SPLIT * CH * 4;
    int*   Pout    = (int*)p;                 p += (size_t)NCH * SPLIT * CH * 4;
    int2*  srw     = (int2*)p;                p += (size_t)E * 8;
    float* t1      = (float*)p;               p += (size_t)N * 128 * 4;  // also t2
    float* h1      = (float*)p;               p += (size_t)N * 128 * 4;
    float* h2      = (float*)p;               p += (size_t)N * 64 * 4;
    float* part    = (float*)p;               p += (size_t)RB * 128 * 64 * 4;
    int*   pcnt    = (int*)p;                 /* RB*128 ints */

    k_hist<<<NCH * SPLIT, 512, 0, stream>>>(src, dst, Pin, Pout, E, epb);
    k_hredscan<<<NB, 256, 0, stream>>>(Pin, Pout, cin, nin, nout, excl, bsum, N);
    k_scan2<<<1, 256, 0, stream>>>(bsum, boff, NB);
    k_scan3<<<NB, 256, 0, stream>>>(excl, boff, row_off, N);
    k_fillr<<<NCH * SPLIT, 512, 0, stream>>>(src, dst, ew, nout, Pin, row_off,
                                             srw, E, epb);

    k_gemm<128, 8><<<(N + 63) / 64, 256, 0, stream>>>(x, W1, t1, N, 128);
    k_agg<128, 32><<<(N + 7) / 8, 256, 0, stream>>>(row_off, cin, srw, nin, t1, h1, N);

    k_gemm<64, 4><<<(N + 63) / 64, 256, 0, stream>>>(h1, W2, t1, N, 128);
    k_agg<64, 16><<<(N + 15) / 16, 256, 0, stream>>>(row_off, cin, srw, nin, t1, h2, N);

    const int npb = (N + RB - 1) / RB;
    k_rpart<<<RB, 256, 0, stream>>>(h2, gid, part, pcnt, N, npb);
    k_rfinal<<<(128 * 64 + 255) / 256, 256, 0, stream>>>(part, pcnt, (float*)d_out,
                                                         128 * 64);
}

// Round 15
// 273.691 us; speedup vs baseline: 1.5221x; 1.0035x over previous
//
#include <hip/hip_runtime.h>

// ---------------------------------------------------------------------------
// 2-layer GraphConv (DGL norm='both') + per-graph mean readout.
// R14: k_agg ILP test FAILED (6-wide 44.3 vs 4-wide 43.4, both ~134MB fabric
// traffic @3.7TB/s) -> k_agg is fabric-BW-bound at its random-gather floor;
// reverted to 4-wide. New lever: k_gemm inner loop was 4 scalar ds_read_b32
// per k-step; store X tile TRANSPOSED [BK][BM+4] -> single ds_read_b128
// (broadcast, conflict-free). Build phase unchanged (R12: 512thr, SPLIT=32,
// int4; zero global atomics per R6: random atomics ~23.5M/ms, 31B RMW).
// Pipeline:
//   1. k_hist:      dual LDS hist per (chunk,split) -> Pin/Pout partials
//   2. k_hredscan:  cin + nin/nout + per-split offsets + block scan (fused)
//   3. k_scan2/3:   row offsets
//   4. k_fillr:     srw[pos] = {src, nout[src]*ew}, pos atomic-free
//   5. k_gemm<128>: t1 = x @ W1        (transposed-Xs, b128 LDS reads)
//   6. k_agg<128,32>: h1 = leaky(nin * gather-sum(t1))   [4-wide, 2 acc]
//   7. k_gemm<64>:  t2 = h1 @ W2
//   8. k_agg<64,16>: h2
//   9. k_rpart / k_rfinal: per-graph mean via LDS partials
// ---------------------------------------------------------------------------

#define LB256 __launch_bounds__(256)
#define LB512 __launch_bounds__(512)

constexpr int RB = 256;        // readout partial blocks (full-chip)
constexpr int CH = 8192;       // nodes per histogram chunk (32KB LDS per hist)
constexpr int CHB = 13;        // log2(CH)
constexpr int SPLIT = 32;      // edge slices per chunk (grid = NCH*SPLIT = 224)

__device__ __forceinline__ float leaky(float v) { return v > 0.f ? v : 0.01f * v; }

// Dual LDS histogram: in-degree (dst) and out-degree (src) partials.
// 512 threads, int4 edge loads. epb is a multiple of 4.
__global__ LB512 void k_hist(const int* __restrict__ src, const int* __restrict__ dst,
                             int* __restrict__ Pin, int* __restrict__ Pout,
                             int E, int epb) {
    __shared__ int hin[CH];
    __shared__ int hout[CH];
    const int c = blockIdx.x / SPLIT;
    const int s = blockIdx.x % SPLIT;
    const int t = threadIdx.x;
    const int4 z{0, 0, 0, 0};
    for (int i = t; i < CH / 4; i += 512) {
        ((int4*)hin)[i] = z;
        ((int4*)hout)[i] = z;
    }
    __syncthreads();

    const int base = c << CHB;
    const int e0 = s * epb;
    const int e1 = min(E, e0 + epb);
    if (e0 < e1) {
        const int nv = (e1 - e0) >> 2;  // int4 count
        const int4* d4 = (const int4*)(dst + e0);
        const int4* s4 = (const int4*)(src + e0);
        for (int i = t; i < nv; i += 512) {
            const int4 dd = d4[i], ss = s4[i];
            int v;
            v = dd.x - base; if ((unsigned)v < (unsigned)CH) atomicAdd(&hin[v], 1);
            v = dd.y - base; if ((unsigned)v < (unsigned)CH) atomicAdd(&hin[v], 1);
            v = dd.z - base; if ((unsigned)v < (unsigned)CH) atomicAdd(&hin[v], 1);
            v = dd.w - base; if ((unsigned)v < (unsigned)CH) atomicAdd(&hin[v], 1);
            v = ss.x - base; if ((unsigned)v < (unsigned)CH) atomicAdd(&hout[v], 1);
            v = ss.y - base; if ((unsigned)v < (unsigned)CH) atomicAdd(&hout[v], 1);
            v = ss.z - base; if ((unsigned)v < (unsigned)CH) atomicAdd(&hout[v], 1);
            v = ss.w - base; if ((unsigned)v < (unsigned)CH) atomicAdd(&hout[v], 1);
        }
        for (int e = e0 + (nv << 2) + t; e < e1; e += 512) {  // scalar tail
            int v = dst[e] - base; if ((unsigned)v < (unsigned)CH) atomicAdd(&hin[v], 1);
            v = src[e] - base;     if ((unsigned)v < (unsigned)CH) atomicAdd(&hout[v], 1);
        }
    }
    __syncthreads();

    int4* pi = (int4*)&Pin[((size_t)c * SPLIT + s) * CH];
    int4* po = (int4*)&Pout[((size_t)c * SPLIT + s) * CH];
    for (int i = t; i < CH / 4; i += 512) {
        pi[i] = ((const int4*)hin)[i];
        po[i] = ((const int4*)hout)[i];
    }
}

// inclusive block scan helper across 256 threads
__device__ __forceinline__ int block_scan_incl(int v, int t) {
    const int lane = t & 63, w = t >> 6;
#pragma unroll
    for (int off = 1; off < 64; off <<= 1) {
        int n = __shfl_up(v, off);
        if (lane >= off) v += n;
    }
    __shared__ int wsum[4];
    if (lane == 63) wsum[w] = v;
    __syncthreads();
    int base = 0;
#pragma unroll
    for (int k = 0; k < 4; ++k)
        if (k < w) base += wsum[k];
    return v + base;
}

// Fused: per-node reduce of Pin/Pout (Pin -> exclusive split offsets in
// place), degree norms, AND block-level inclusive scan of cin.
__global__ LB256 void k_hredscan(int* __restrict__ Pin, const int* __restrict__ Pout,
                                 int* __restrict__ cin, float* __restrict__ nin,
                                 float* __restrict__ nout, int* __restrict__ excl,
                                 int* __restrict__ bsum, int N) {
    const int t = threadIdx.x, i = blockIdx.x * 256 + t;
    int acc = 0;
    if (i < N) {
        const int c = i >> CHB, l = i & (CH - 1);
        const size_t base = (size_t)c * SPLIT * CH + l;
#pragma unroll
        for (int s = 0; s < SPLIT; ++s) {
            const size_t idx = base + (size_t)s * CH;
            const int v = Pin[idx];
            Pin[idx] = acc;          // exclusive offset of split s within row i
            acc += v;
        }
        int ao = 0;
#pragma unroll
        for (int s = 0; s < SPLIT; ++s) ao += Pout[base + (size_t)s * CH];
        cin[i] = acc;
        nin[i]  = rsqrtf(fmaxf((float)acc, 1.f));
        nout[i] = rsqrtf(fmaxf((float)ao, 1.f));
    }
    const int incl = block_scan_incl(acc, t);  // acc==0 for i>=N
    if (i < N) excl[i] = incl - acc;
    if (t == 255) bsum[blockIdx.x] = incl;
}

__global__ LB256 void k_scan2(const int* __restrict__ bsum, int* __restrict__ boff, int NB) {
    const int t = threadIdx.x;
    const int orig = (t < NB) ? bsum[t] : 0;
    const int incl = block_scan_incl(orig, t);
    if (t < NB) boff[t] = incl - orig;
}

__global__ LB256 void k_scan3(const int* __restrict__ excl, const int* __restrict__ boff,
                              int* __restrict__ row_off, int N) {
    const int i = blockIdx.x * 256 + threadIdx.x;
    if (i < N) row_off[i] = excl[i] + boff[blockIdx.x];
}

// Rank-replay fill: same (chunk,split) decomposition as k_hist; LDS rank +
// precomputed split offset -> unique position, no global atomics.
__global__ LB512 void k_fillr(const int* __restrict__ src, const int* __restrict__ dst,
                              const float* __restrict__ ew, const float* __restrict__ nout,
                              const int* __restrict__ Pin, const int* __restrict__ row_off,
                              int2* __restrict__ srw, int E, int epb) {
    __shared__ int h[CH];
    const int c = blockIdx.x / SPLIT;
    const int s = blockIdx.x % SPLIT;
    const int t = threadIdx.x;
    const int4 z{0, 0, 0, 0};
    for (int i = t; i < CH / 4; i += 512) ((int4*)h)[i] = z;
    __syncthreads();

    const int base = c << CHB;
    const int e0 = s * epb;
    const int e1 = min(E, e0 + epb);
    const int* off = &Pin[((size_t)c * SPLIT + s) * CH];
    if (e0 < e1) {
        const int nv = (e1 - e0) >> 2;
        const int4* d4 = (const int4*)(dst + e0);
        const int4* s4 = (const int4*)(src + e0);
        const float4* w4 = (const float4*)(ew + e0);
        for (int i = t; i < nv; i += 512) {
            const int4 dd = d4[i], ss = s4[i];
            const float4 ww = w4[i];
#define FILL1(D, S, W)                                                       \
            {                                                                \
                const int dl = (D) - base;                                   \
                if ((unsigned)dl < (unsigned)CH) {                           \
                    const int r = atomicAdd(&h[dl], 1);                      \
                    const int pos = row_off[D] + off[dl] + r;                \
                    srw[pos] = make_int2((S), __float_as_int(nout[S] * (W)));\
                }                                                            \
            }
            FILL1(dd.x, ss.x, ww.x)
            FILL1(dd.y, ss.y, ww.y)
            FILL1(dd.z, ss.z, ww.z)
            FILL1(dd.w, ss.w, ww.w)
        }
        for (int e = e0 + (nv << 2) + t; e < e1; e += 512) {  // scalar tail
            FILL1(dst[e], src[e], ew[e])
        }
#undef FILL1
    }
}

// C[N][BN] = A[N][K] @ W[K][BN].  BM=64, BK=32, 256 thr as 16x16, 4xTN regs.
// R14: X tile stored TRANSPOSED Xs[BK][BM+4] (pad 4 -> 272B row stride keeps
// 16B alignment). Inner loop xv = one ds_read_b128 (broadcast across the 16
// lanes sharing ty), replacing 4 scalar ds_read_b32.
template <int BN, int TN>
__global__ LB256 void k_gemm(const float* __restrict__ A, const float* __restrict__ W,
                             float* __restrict__ C, int N, int K) {
    constexpr int BM = 64, BK = 32;
    __shared__ float Xs[BK][BM + 4];   // transposed: [k][row]
    __shared__ float Ws[BK][BN];

    const int tid = threadIdx.x;
    const int r0 = blockIdx.x * BM;
    const int ty = tid >> 4;
    const int tx = tid & 15;

    float acc[4][TN];
#pragma unroll
    for (int i = 0; i < 4; ++i)
#pragma unroll
        for (int j = 0; j < TN; ++j) acc[i][j] = 0.f;

    const int lrow = tid >> 2;         // 0..63: X-tile row this thread stages
    const int lc = (tid & 3) * 4;      // k-offset of first float4
    const int kr = tid >> 3;

    for (int kc = 0; kc < K; kc += BK) {
        const int gr = r0 + lrow;
        float4 v0{0.f, 0.f, 0.f, 0.f}, v1{0.f, 0.f, 0.f, 0.f};
        if (gr < N) {
            v0 = *(const float4*)&A[(size_t)gr * K + kc + lc];
            v1 = *(const float4*)&A[(size_t)gr * K + kc + lc + 16];
        }
        // transposed store: Xs[k][row]
        Xs[lc + 0][lrow] = v0.x;  Xs[lc + 1][lrow] = v0.y;
        Xs[lc + 2][lrow] = v0.z;  Xs[lc + 3][lrow] = v0.w;
        Xs[lc + 16][lrow] = v1.x; Xs[lc + 17][lrow] = v1.y;
        Xs[lc + 18][lrow] = v1.z; Xs[lc + 19][lrow] = v1.w;
#pragma unroll
        for (int j = 0; j < BN / 32; ++j) {
            const int c4 = (tid & 7) + j * 8;
            *(float4*)&Ws[kr][c4 * 4] =
                *(const float4*)&W[(size_t)(kc + kr) * BN + c4 * 4];
        }
        __syncthreads();

#pragma unroll
        for (int k = 0; k < BK; ++k) {
            const float4 xq = *(const float4*)&Xs[k][ty * 4];  // b128, broadcast
            float xv[4] = {xq.x, xq.y, xq.z, xq.w};
            float wv[TN];
#pragma unroll
            for (int j4 = 0; j4 < TN / 4; ++j4) {
                const float4 w4 = *(const float4*)&Ws[k][tx * TN + j4 * 4];
                wv[j4 * 4 + 0] = w4.x; wv[j4 * 4 + 1] = w4.y;
                wv[j4 * 4 + 2] = w4.z; wv[j4 * 4 + 3] = w4.w;
            }
#pragma unroll
            for (int i = 0; i < 4; ++i)
#pragma unroll
                for (int j = 0; j < TN; ++j) acc[i][j] = fmaf(xv[i], wv[j], acc[i][j]);
        }
        __syncthreads();
    }

#pragma unroll
    for (int i = 0; i < 4; ++i) {
        const int r = r0 + ty * 4 + i;
        if (r < N) {
#pragma unroll
            for (int j4 = 0; j4 < TN / 4; ++j4) {
                float4 o{acc[i][j4 * 4 + 0], acc[i][j4 * 4 + 1],
                         acc[i][j4 * 4 + 2], acc[i][j4 * 4 + 3]};
                *(float4*)&C[(size_t)r * BN + tx * TN + j4 * 4] = o;
            }
        }
    }
}

// Pull-aggregate: one LANES-lane group per node, float4 per lane, 4-wide ILP
// with 2 accumulators (R13-measured best: 28 VGPR, 66% occ, 43.4us).
// out[n] = leaky(nin[n] * sum_j w[j] * h[s[j]]), records srw = {s, w}.
template <int F, int LANES>
__global__ LB256 void k_agg(const int* __restrict__ row_off, const int* __restrict__ cnt,
                            const int2* __restrict__ srw, const float* __restrict__ nin,
                            const float* __restrict__ h, float* __restrict__ out, int N) {
    const int node = blockIdx.x * (256 / LANES) + threadIdx.x / LANES;
    if (node >= N) return;
    const int lane = threadIdx.x % LANES;
    const int start = row_off[node], len = cnt[node];

    float4 accA{0.f, 0.f, 0.f, 0.f}, accB{0.f, 0.f, 0.f, 0.f};
    int j = 0;
    for (; j + 3 < len; j += 4) {
        const int b = start + j;
        const int2 r0_ = srw[b + 0], r1_ = srw[b + 1], r2_ = srw[b + 2], r3_ = srw[b + 3];
        const float c0 = __int_as_float(r0_.y), c1 = __int_as_float(r1_.y);
        const float c2 = __int_as_float(r2_.y), c3 = __int_as_float(r3_.y);
        const float4 v0 = *(const float4*)&h[(size_t)r0_.x * F + lane * 4];
        const float4 v1 = *(const float4*)&h[(size_t)r1_.x * F + lane * 4];
        const float4 v2 = *(const float4*)&h[(size_t)r2_.x * F + lane * 4];
        const float4 v3 = *(const float4*)&h[(size_t)r3_.x * F + lane * 4];
        accA.x = fmaf(c0, v0.x, fmaf(c1, v1.x, accA.x));
        accA.y = fmaf(c0, v0.y, fmaf(c1, v1.y, accA.y));
        accA.z = fmaf(c0, v0.z, fmaf(c1, v1.z, accA.z));
        accA.w = fmaf(c0, v0.w, fmaf(c1, v1.w, accA.w));
        accB.x = fmaf(c2, v2.x, fmaf(c3, v3.x, accB.x));
        accB.y = fmaf(c2, v2.y, fmaf(c3, v3.y, accB.y));
        accB.z = fmaf(c2, v2.z, fmaf(c3, v3.z, accB.z));
        accB.w = fmaf(c2, v2.w, fmaf(c3, v3.w, accB.w));
    }
    for (; j < len; ++j) {
        const int2 r0_ = srw[start + j];
        const float c0 = __int_as_float(r0_.y);
        const float4 v0 = *(const float4*)&h[(size_t)r0_.x * F + lane * 4];
        accA.x = fmaf(c0, v0.x, accA.x);
        accA.y = fmaf(c0, v0.y, accA.y);
        accA.z = fmaf(c0, v0.z, accA.z);
        accA.w = fmaf(c0, v0.w, accA.w);
    }
    const float nd = nin[node];
    float4 o{leaky((accA.x + accB.x) * nd), leaky((accA.y + accB.y) * nd),
             leaky((accA.z + accB.z) * nd), leaky((accA.w + accB.w) * nd)};
    *(float4*)&out[(size_t)node * F + lane * 4] = o;
}

// Per-block LDS histogram over (graph, feat); coalesced partial dump.
__global__ LB256 void k_rpart(const float* __restrict__ h2, const int* __restrict__ gid,
                              float* __restrict__ part, int* __restrict__ pcnt,
                              int N, int npb) {
    __shared__ float lsum[128 * 64];
    __shared__ int lcnt[128];
    const int t = threadIdx.x;
    for (int i = t; i < 128 * 64; i += 256) lsum[i] = 0.f;
    if (t < 128) lcnt[t] = 0;
    __syncthreads();

    const int n0 = blockIdx.x * npb;
    const int n1 = min(N, n0 + npb);
    const int ty = t >> 6, lane = t & 63;
    for (int n = n0 + ty; n < n1; n += 4) {
        const int g = gid[n];
        atomicAdd(&lsum[g * 64 + lane], h2[(size_t)n * 64 + lane]);
        if (lane == 0) atomicAdd(&lcnt[g], 1);
    }
    __syncthreads();

    float* op = &part[(size_t)blockIdx.x * (128 * 64)];
    for (int i = t; i < 128 * 64; i += 256) op[i] = lsum[i];
    if (t < 128) pcnt[blockIdx.x * 128 + t] = lcnt[t];
}

__global__ LB256 void k_rfinal(const float* __restrict__ part, const int* __restrict__ pcnt,
                               float* __restrict__ out, int total) {
    const int i = blockIdx.x * 256 + threadIdx.x;
    if (i >= total) return;
    const int g = i >> 6;
    float s = 0.f;
    int c = 0;
#pragma unroll 4
    for (int b = 0; b < RB; ++b) {
        s += part[(size_t)b * (128 * 64) + i];
        c += pcnt[b * 128 + g];
    }
    out[i] = s / fmaxf((float)c, 1.f);
}

extern "C" void kernel_launch(void* const* d_in, const int* in_sizes, int n_in,
                              void* d_out, int out_size, void* d_ws, size_t ws_size,
                              hipStream_t stream) {
    const float* x   = (const float*)d_in[0];
    const float* ew  = (const float*)d_in[1];
    const float* W1  = (const float*)d_in[2];
    const float* W2  = (const float*)d_in[3];
    const int*   src = (const int*)d_in[4];
    const int*   dst = (const int*)d_in[5];
    const int*   gid = (const int*)d_in[6];

    const int N  = in_sizes[6];      // 50000
    const int E  = in_sizes[4];      // 600000
    const int NB = (N + 255) / 256;  // 196
    const int Na = (N + 63) & ~63;
    const int NCH = (N + CH - 1) / CH;                       // 7 chunks
    const int epb = (((E + SPLIT - 1) / SPLIT) + 3) & ~3;    // mult-of-4 slice

    // ---- workspace layout (no memset needed; everything fully written) ----
    char* p = (char*)d_ws;
    int*   cin     = (int*)p;                 p += (size_t)Na * 4;
    int*   excl    = (int*)p;                 p += (size_t)Na * 4;
    int*   bsum    = (int*)p;                 p += 256 * 4;
    int*   boff    = (int*)p;                 p += 256 * 4;
    int*   row_off = (int*)p;                 p += (size_t)Na * 4;
    float* nin     = (float*)p;               p += (size_t)Na * 4;
    float* nout    = (float*)p;               p += (size_t)Na * 4;
    int*   Pin     = (int*)p;                 p += (size_t)NCH * SPLIT * CH * 4;
    int*   Pout    = (int*)p;                 p += (size_t)NCH * SPLIT * CH * 4;
    int2*  srw     = (int2*)p;                p += (size_t)E * 8;
    float* t1      = (float*)p;               p += (size_t)N * 128 * 4;  // also t2
    float* h1      = (float*)p;               p += (size_t)N * 128 * 4;
    float* h2      = (float*)p;               p += (size_t)N * 64 * 4;
    float* part    = (float*)p;               p += (size_t)RB * 128 * 64 * 4;
    int*   pcnt    = (int*)p;                 /* RB*128 ints */

    k_hist<<<NCH * SPLIT, 512, 0, stream>>>(src, dst, Pin, Pout, E, epb);
    k_hredscan<<<NB, 256, 0, stream>>>(Pin, Pout, cin, nin, nout, excl, bsum, N);
    k_scan2<<<1, 256, 0, stream>>>(bsum, boff, NB);
    k_scan3<<<NB, 256, 0, stream>>>(excl, boff, row_off, N);
    k_fillr<<<NCH * SPLIT, 512, 0, stream>>>(src, dst, ew, nout, Pin, row_off,
                                             srw, E, epb);

    k_gemm<128, 8><<<(N + 63) / 64, 256, 0, stream>>>(x, W1, t1, N, 128);
    k_agg<128, 32><<<(N + 7) / 8, 256, 0, stream>>>(row_off, cin, srw, nin, t1, h1, N);

    k_gemm<64, 4><<<(N + 63) / 64, 256, 0, stream>>>(h1, W2, t1, N, 128);
    k_agg<64, 16><<<(N + 15) / 16, 256, 0, stream>>>(row_off, cin, srw, nin, t1, h2, N);

    const int npb = (N + RB - 1) / RB;
    k_rpart<<<RB, 256, 0, stream>>>(h2, gid, part, pcnt, N, npb);
    k_rfinal<<<(128 * 64 + 255) / 256, 256, 0, stream>>>(part, pcnt, (float*)d_out,
                                                         128 * 64);
}

// Round 16
// 252.174 us; speedup vs baseline: 1.6520x; 1.0853x over previous
//
#include <hip/hip_runtime.h>

// ---------------------------------------------------------------------------
// 2-layer GraphConv (DGL norm='both') + per-graph mean readout.
// R15: k_agg proven fabric-BW-bound (3 configs within 2%: 134MB L2-miss @
// ~3.7TB/s). Only lever left: halve the payload. t1/h1/t2 stored as bf16
// (RNE); ALL math (weights, FMA, accumulation, norms) stays fp32. Gather
// lane reads 8B (4 bf16) -- still fully coalesced. GEMM writes + gemm2 reads
// halve too. Build phase unchanged (R12: 512thr, SPLIT=32, int4; zero global
// atomics per R6: random atomics ~23.5M/ms, 31B RMW).
// Pipeline:
//   1. k_hist:      dual LDS hist per (chunk,split) -> Pin/Pout partials
//   2. k_hredscan:  cin + nin/nout + per-split offsets + block scan (fused)
//   3. k_scan2/3:   row offsets
//   4. k_fillr:     srw[pos] = {src, nout[src]*ew}, pos atomic-free
//   5. k_gemm<128,8,f32in>:  t1(bf16) = x @ W1      (transposed-Xs, b128)
//   6. k_agg<128,32,->bf16>: h1(bf16) = leaky(nin * gather-sum(t1))
//   7. k_gemm<64,4,bf16in>:  t2(bf16) = h1 @ W2
//   8. k_agg<64,16,->f32>:   h2(f32)
//   9. k_rpart / k_rfinal: per-graph mean via LDS partials
// ---------------------------------------------------------------------------

#define LB256 __launch_bounds__(256)
#define LB512 __launch_bounds__(512)

typedef unsigned short ushort_t;

constexpr int RB = 256;        // readout partial blocks (full-chip)
constexpr int CH = 8192;       // nodes per histogram chunk (32KB LDS per hist)
constexpr int CHB = 13;        // log2(CH)
constexpr int SPLIT = 32;      // edge slices per chunk (grid = NCH*SPLIT = 224)

__device__ __forceinline__ float leaky(float v) { return v > 0.f ? v : 0.01f * v; }

// bf16 helpers: RNE pack (low = a, high = b), cheap unpack.
__device__ __forceinline__ unsigned pack_bf16x2(float a, float b) {
    unsigned ua = __float_as_uint(a);
    unsigned ub = __float_as_uint(b);
    ua = (ua + 0x7fffu + ((ua >> 16) & 1u)) >> 16;
    ub = (ub + 0x7fffu + ((ub >> 16) & 1u)) & 0xffff0000u;
    return ua | ub;
}
__device__ __forceinline__ float lo_bf16(unsigned u) { return __uint_as_float(u << 16); }
__device__ __forceinline__ float hi_bf16(unsigned u) { return __uint_as_float(u & 0xffff0000u); }

// Dual LDS histogram: in-degree (dst) and out-degree (src) partials.
__global__ LB512 void k_hist(const int* __restrict__ src, const int* __restrict__ dst,
                             int* __restrict__ Pin, int* __restrict__ Pout,
                             int E, int epb) {
    __shared__ int hin[CH];
    __shared__ int hout[CH];
    const int c = blockIdx.x / SPLIT;
    const int s = blockIdx.x % SPLIT;
    const int t = threadIdx.x;
    const int4 z{0, 0, 0, 0};
    for (int i = t; i < CH / 4; i += 512) {
        ((int4*)hin)[i] = z;
        ((int4*)hout)[i] = z;
    }
    __syncthreads();

    const int base = c << CHB;
    const int e0 = s * epb;
    const int e1 = min(E, e0 + epb);
    if (e0 < e1) {
        const int nv = (e1 - e0) >> 2;  // int4 count
        const int4* d4 = (const int4*)(dst + e0);
        const int4* s4 = (const int4*)(src + e0);
        for (int i = t; i < nv; i += 512) {
            const int4 dd = d4[i], ss = s4[i];
            int v;
            v = dd.x - base; if ((unsigned)v < (unsigned)CH) atomicAdd(&hin[v], 1);
            v = dd.y - base; if ((unsigned)v < (unsigned)CH) atomicAdd(&hin[v], 1);
            v = dd.z - base; if ((unsigned)v < (unsigned)CH) atomicAdd(&hin[v], 1);
            v = dd.w - base; if ((unsigned)v < (unsigned)CH) atomicAdd(&hin[v], 1);
            v = ss.x - base; if ((unsigned)v < (unsigned)CH) atomicAdd(&hout[v], 1);
            v = ss.y - base; if ((unsigned)v < (unsigned)CH) atomicAdd(&hout[v], 1);
            v = ss.z - base; if ((unsigned)v < (unsigned)CH) atomicAdd(&hout[v], 1);
            v = ss.w - base; if ((unsigned)v < (unsigned)CH) atomicAdd(&hout[v], 1);
        }
        for (int e = e0 + (nv << 2) + t; e < e1; e += 512) {  // scalar tail
            int v = dst[e] - base; if ((unsigned)v < (unsigned)CH) atomicAdd(&hin[v], 1);
            v = src[e] - base;     if ((unsigned)v < (unsigned)CH) atomicAdd(&hout[v], 1);
        }
    }
    __syncthreads();

    int4* pi = (int4*)&Pin[((size_t)c * SPLIT + s) * CH];
    int4* po = (int4*)&Pout[((size_t)c * SPLIT + s) * CH];
    for (int i = t; i < CH / 4; i += 512) {
        pi[i] = ((const int4*)hin)[i];
        po[i] = ((const int4*)hout)[i];
    }
}

// inclusive block scan helper across 256 threads
__device__ __forceinline__ int block_scan_incl(int v, int t) {
    const int lane = t & 63, w = t >> 6;
#pragma unroll
    for (int off = 1; off < 64; off <<= 1) {
        int n = __shfl_up(v, off);
        if (lane >= off) v += n;
    }
    __shared__ int wsum[4];
    if (lane == 63) wsum[w] = v;
    __syncthreads();
    int base = 0;
#pragma unroll
    for (int k = 0; k < 4; ++k)
        if (k < w) base += wsum[k];
    return v + base;
}

// Fused: per-node reduce of Pin/Pout (Pin -> exclusive split offsets in
// place), degree norms, AND block-level inclusive scan of cin.
__global__ LB256 void k_hredscan(int* __restrict__ Pin, const int* __restrict__ Pout,
                                 int* __restrict__ cin, float* __restrict__ nin,
                                 float* __restrict__ nout, int* __restrict__ excl,
                                 int* __restrict__ bsum, int N) {
    const int t = threadIdx.x, i = blockIdx.x * 256 + t;
    int acc = 0;
    if (i < N) {
        const int c = i >> CHB, l = i & (CH - 1);
        const size_t base = (size_t)c * SPLIT * CH + l;
#pragma unroll
        for (int s = 0; s < SPLIT; ++s) {
            const size_t idx = base + (size_t)s * CH;
            const int v = Pin[idx];
            Pin[idx] = acc;          // exclusive offset of split s within row i
            acc += v;
        }
        int ao = 0;
#pragma unroll
        for (int s = 0; s < SPLIT; ++s) ao += Pout[base + (size_t)s * CH];
        cin[i] = acc;
        nin[i]  = rsqrtf(fmaxf((float)acc, 1.f));
        nout[i] = rsqrtf(fmaxf((float)ao, 1.f));
    }
    const int incl = block_scan_incl(acc, t);  // acc==0 for i>=N
    if (i < N) excl[i] = incl - acc;
    if (t == 255) bsum[blockIdx.x] = incl;
}

__global__ LB256 void k_scan2(const int* __restrict__ bsum, int* __restrict__ boff, int NB) {
    const int t = threadIdx.x;
    const int orig = (t < NB) ? bsum[t] : 0;
    const int incl = block_scan_incl(orig, t);
    if (t < NB) boff[t] = incl - orig;
}

__global__ LB256 void k_scan3(const int* __restrict__ excl, const int* __restrict__ boff,
                              int* __restrict__ row_off, int N) {
    const int i = blockIdx.x * 256 + threadIdx.x;
    if (i < N) row_off[i] = excl[i] + boff[blockIdx.x];
}

// Rank-replay fill: LDS rank + precomputed split offset -> unique position.
__global__ LB512 void k_fillr(const int* __restrict__ src, const int* __restrict__ dst,
                              const float* __restrict__ ew, const float* __restrict__ nout,
                              const int* __restrict__ Pin, const int* __restrict__ row_off,
                              int2* __restrict__ srw, int E, int epb) {
    __shared__ int h[CH];
    const int c = blockIdx.x / SPLIT;
    const int s = blockIdx.x % SPLIT;
    const int t = threadIdx.x;
    const int4 z{0, 0, 0, 0};
    for (int i = t; i < CH / 4; i += 512) ((int4*)h)[i] = z;
    __syncthreads();

    const int base = c << CHB;
    const int e0 = s * epb;
    const int e1 = min(E, e0 + epb);
    const int* off = &Pin[((size_t)c * SPLIT + s) * CH];
    if (e0 < e1) {
        const int nv = (e1 - e0) >> 2;
        const int4* d4 = (const int4*)(dst + e0);
        const int4* s4 = (const int4*)(src + e0);
        const float4* w4 = (const float4*)(ew + e0);
        for (int i = t; i < nv; i += 512) {
            const int4 dd = d4[i], ss = s4[i];
            const float4 ww = w4[i];
#define FILL1(D, S, W)                                                       \
            {                                                                \
                const int dl = (D) - base;                                   \
                if ((unsigned)dl < (unsigned)CH) {                           \
                    const int r = atomicAdd(&h[dl], 1);                      \
                    const int pos = row_off[D] + off[dl] + r;                \
                    srw[pos] = make_int2((S), __float_as_int(nout[S] * (W)));\
                }                                                            \
            }
            FILL1(dd.x, ss.x, ww.x)
            FILL1(dd.y, ss.y, ww.y)
            FILL1(dd.z, ss.z, ww.z)
            FILL1(dd.w, ss.w, ww.w)
        }
        for (int e = e0 + (nv << 2) + t; e < e1; e += 512) {  // scalar tail
            FILL1(dst[e], src[e], ew[e])
        }
#undef FILL1
    }
}

// C16[N][BN] (bf16) = A[N][K] @ W[K][BN].  BM=64, BK=32, 256 thr as 16x16.
// Transposed Xs[BK][BM+4] -> inner-loop ds_read_b128 broadcast (R14).
// IN_BF16: A is bf16 (h1); else f32. Output always bf16 (RNE).
template <int BN, int TN, bool IN_BF16>
__global__ LB256 void k_gemm(const void* __restrict__ A, const float* __restrict__ W,
                             ushort_t* __restrict__ C16, int N, int K) {
    constexpr int BM = 64, BK = 32;
    __shared__ float Xs[BK][BM + 4];   // transposed: [k][row]
    __shared__ float Ws[BK][BN];

    const int tid = threadIdx.x;
    const int r0 = blockIdx.x * BM;
    const int ty = tid >> 4;
    const int tx = tid & 15;

    float acc[4][TN];
#pragma unroll
    for (int i = 0; i < 4; ++i)
#pragma unroll
        for (int j = 0; j < TN; ++j) acc[i][j] = 0.f;

    const int lrow = tid >> 2;         // 0..63: X-tile row this thread stages
    const int kr = tid >> 3;

    for (int kc = 0; kc < K; kc += BK) {
        const int gr = r0 + lrow;
        if constexpr (IN_BF16) {
            const int kb = (tid & 3) * 8;    // 8 contiguous k per thread
            uint4 v{0u, 0u, 0u, 0u};
            if (gr < N)
                v = *(const uint4*)&((const ushort_t*)A)[(size_t)gr * K + kc + kb];
            Xs[kb + 0][lrow] = lo_bf16(v.x); Xs[kb + 1][lrow] = hi_bf16(v.x);
            Xs[kb + 2][lrow] = lo_bf16(v.y); Xs[kb + 3][lrow] = hi_bf16(v.y);
            Xs[kb + 4][lrow] = lo_bf16(v.z); Xs[kb + 5][lrow] = hi_bf16(v.z);
            Xs[kb + 6][lrow] = lo_bf16(v.w); Xs[kb + 7][lrow] = hi_bf16(v.w);
        } else {
            const int lc = (tid & 3) * 4;
            float4 v0{0.f, 0.f, 0.f, 0.f}, v1{0.f, 0.f, 0.f, 0.f};
            if (gr < N) {
                v0 = *(const float4*)&((const float*)A)[(size_t)gr * K + kc + lc];
                v1 = *(const float4*)&((const float*)A)[(size_t)gr * K + kc + lc + 16];
            }
            Xs[lc + 0][lrow] = v0.x;  Xs[lc + 1][lrow] = v0.y;
            Xs[lc + 2][lrow] = v0.z;  Xs[lc + 3][lrow] = v0.w;
            Xs[lc + 16][lrow] = v1.x; Xs[lc + 17][lrow] = v1.y;
            Xs[lc + 18][lrow] = v1.z; Xs[lc + 19][lrow] = v1.w;
        }
#pragma unroll
        for (int j = 0; j < BN / 32; ++j) {
            const int c4 = (tid & 7) + j * 8;
            *(float4*)&Ws[kr][c4 * 4] =
                *(const float4*)&W[(size_t)(kc + kr) * BN + c4 * 4];
        }
        __syncthreads();

#pragma unroll
        for (int k = 0; k < BK; ++k) {
            const float4 xq = *(const float4*)&Xs[k][ty * 4];  // b128, broadcast
            float xv[4] = {xq.x, xq.y, xq.z, xq.w};
            float wv[TN];
#pragma unroll
            for (int j4 = 0; j4 < TN / 4; ++j4) {
                const float4 w4 = *(const float4*)&Ws[k][tx * TN + j4 * 4];
                wv[j4 * 4 + 0] = w4.x; wv[j4 * 4 + 1] = w4.y;
                wv[j4 * 4 + 2] = w4.z; wv[j4 * 4 + 3] = w4.w;
            }
#pragma unroll
            for (int i = 0; i < 4; ++i)
#pragma unroll
                for (int j = 0; j < TN; ++j) acc[i][j] = fmaf(xv[i], wv[j], acc[i][j]);
        }
        __syncthreads();
    }

#pragma unroll
    for (int i = 0; i < 4; ++i) {
        const int r = r0 + ty * 4 + i;
        if (r < N) {
            if constexpr (TN == 8) {
                uint4 w{pack_bf16x2(acc[i][0], acc[i][1]), pack_bf16x2(acc[i][2], acc[i][3]),
                        pack_bf16x2(acc[i][4], acc[i][5]), pack_bf16x2(acc[i][6], acc[i][7])};
                *(uint4*)&C16[(size_t)r * BN + tx * TN] = w;           // 16B
            } else {
                uint2 w{pack_bf16x2(acc[i][0], acc[i][1]), pack_bf16x2(acc[i][2], acc[i][3])};
                *(uint2*)&C16[(size_t)r * BN + tx * TN] = w;           // 8B
            }
        }
    }
}

// Pull-aggregate over bf16 payload rows; fp32 weights/accum. 4-wide, 2 acc
// (R13-measured best). Lane owns feats [4*lane .. 4*lane+3] (8B uint2 load).
// OUT_BF16: write bf16 (h1); else f32 (h2).
template <int F, int LANES, bool OUT_BF16>
__global__ LB256 void k_agg(const int* __restrict__ row_off, const int* __restrict__ cnt,
                            const int2* __restrict__ srw, const float* __restrict__ nin,
                            const ushort_t* __restrict__ h, void* __restrict__ out, int N) {
    const int node = blockIdx.x * (256 / LANES) + threadIdx.x / LANES;
    if (node >= N) return;
    const int lane = threadIdx.x % LANES;
    const int start = row_off[node], len = cnt[node];
    const int lo4 = lane * 4;

    float a0 = 0.f, a1 = 0.f, a2 = 0.f, a3 = 0.f;
    float b0 = 0.f, b1 = 0.f, b2 = 0.f, b3 = 0.f;
    int j = 0;
    for (; j + 3 < len; j += 4) {
        const int b = start + j;
        const int2 r0_ = srw[b + 0], r1_ = srw[b + 1], r2_ = srw[b + 2], r3_ = srw[b + 3];
        const uint2 q0 = *(const uint2*)&h[(size_t)r0_.x * F + lo4];
        const uint2 q1 = *(const uint2*)&h[(size_t)r1_.x * F + lo4];
        const uint2 q2 = *(const uint2*)&h[(size_t)r2_.x * F + lo4];
        const uint2 q3 = *(const uint2*)&h[(size_t)r3_.x * F + lo4];
        const float c0 = __int_as_float(r0_.y), c1 = __int_as_float(r1_.y);
        const float c2 = __int_as_float(r2_.y), c3 = __int_as_float(r3_.y);
        a0 = fmaf(c0, lo_bf16(q0.x), fmaf(c1, lo_bf16(q1.x), a0));
        a1 = fmaf(c0, hi_bf16(q0.x), fmaf(c1, hi_bf16(q1.x), a1));
        a2 = fmaf(c0, lo_bf16(q0.y), fmaf(c1, lo_bf16(q1.y), a2));
        a3 = fmaf(c0, hi_bf16(q0.y), fmaf(c1, hi_bf16(q1.y), a3));
        b0 = fmaf(c2, lo_bf16(q2.x), fmaf(c3, lo_bf16(q3.x), b0));
        b1 = fmaf(c2, hi_bf16(q2.x), fmaf(c3, hi_bf16(q3.x), b1));
        b2 = fmaf(c2, lo_bf16(q2.y), fmaf(c3, lo_bf16(q3.y), b2));
        b3 = fmaf(c2, hi_bf16(q2.y), fmaf(c3, hi_bf16(q3.y), b3));
    }
    for (; j < len; ++j) {
        const int2 r0_ = srw[start + j];
        const float c0 = __int_as_float(r0_.y);
        const uint2 q0 = *(const uint2*)&h[(size_t)r0_.x * F + lo4];
        a0 = fmaf(c0, lo_bf16(q0.x), a0);
        a1 = fmaf(c0, hi_bf16(q0.x), a1);
        a2 = fmaf(c0, lo_bf16(q0.y), a2);
        a3 = fmaf(c0, hi_bf16(q0.y), a3);
    }
    const float nd = nin[node];
    const float o0 = leaky((a0 + b0) * nd), o1 = leaky((a1 + b1) * nd);
    const float o2 = leaky((a2 + b2) * nd), o3 = leaky((a3 + b3) * nd);
    if constexpr (OUT_BF16) {
        uint2 w{pack_bf16x2(o0, o1), pack_bf16x2(o2, o3)};
        *(uint2*)&((ushort_t*)out)[(size_t)node * F + lo4] = w;
    } else {
        *(float4*)&((float*)out)[(size_t)node * F + lo4] = float4{o0, o1, o2, o3};
    }
}

// Per-block LDS histogram over (graph, feat); coalesced partial dump.
__global__ LB256 void k_rpart(const float* __restrict__ h2, const int* __restrict__ gid,
                              float* __restrict__ part, int* __restrict__ pcnt,
                              int N, int npb) {
    __shared__ float lsum[128 * 64];
    __shared__ int lcnt[128];
    const int t = threadIdx.x;
    for (int i = t; i < 128 * 64; i += 256) lsum[i] = 0.f;
    if (t < 128) lcnt[t] = 0;
    __syncthreads();

    const int n0 = blockIdx.x * npb;
    const int n1 = min(N, n0 + npb);
    const int ty = t >> 6, lane = t & 63;
    for (int n = n0 + ty; n < n1; n += 4) {
        const int g = gid[n];
        atomicAdd(&lsum[g * 64 + lane], h2[(size_t)n * 64 + lane]);
        if (lane == 0) atomicAdd(&lcnt[g], 1);
    }
    __syncthreads();

    float* op = &part[(size_t)blockIdx.x * (128 * 64)];
    for (int i = t; i < 128 * 64; i += 256) op[i] = lsum[i];
    if (t < 128) pcnt[blockIdx.x * 128 + t] = lcnt[t];
}

__global__ LB256 void k_rfinal(const float* __restrict__ part, const int* __restrict__ pcnt,
                               float* __restrict__ out, int total) {
    const int i = blockIdx.x * 256 + threadIdx.x;
    if (i >= total) return;
    const int g = i >> 6;
    float s = 0.f;
    int c = 0;
#pragma unroll 4
    for (int b = 0; b < RB; ++b) {
        s += part[(size_t)b * (128 * 64) + i];
        c += pcnt[b * 128 + g];
    }
    out[i] = s / fmaxf((float)c, 1.f);
}

extern "C" void kernel_launch(void* const* d_in, const int* in_sizes, int n_in,
                              void* d_out, int out_size, void* d_ws, size_t ws_size,
                              hipStream_t stream) {
    const float* x   = (const float*)d_in[0];
    const float* ew  = (const float*)d_in[1];
    const float* W1  = (const float*)d_in[2];
    const float* W2  = (const float*)d_in[3];
    const int*   src = (const int*)d_in[4];
    const int*   dst = (const int*)d_in[5];
    const int*   gid = (const int*)d_in[6];

    const int N  = in_sizes[6];      // 50000
    const int E  = in_sizes[4];      // 600000
    const int NB = (N + 255) / 256;  // 196
    const int Na = (N + 63) & ~63;
    const int NCH = (N + CH - 1) / CH;                       // 7 chunks
    const int epb = (((E + SPLIT - 1) / SPLIT) + 3) & ~3;    // mult-of-4 slice

    // ---- workspace layout (no memset needed; everything fully written) ----
    char* p = (char*)d_ws;
    int*      cin     = (int*)p;              p += (size_t)Na * 4;
    int*      excl    = (int*)p;              p += (size_t)Na * 4;
    int*      bsum    = (int*)p;              p += 256 * 4;
    int*      boff    = (int*)p;              p += 256 * 4;
    int*      row_off = (int*)p;              p += (size_t)Na * 4;
    float*    nin     = (float*)p;            p += (size_t)Na * 4;
    float*    nout    = (float*)p;            p += (size_t)Na * 4;
    int*      Pin     = (int*)p;              p += (size_t)NCH * SPLIT * CH * 4;
    int*      Pout    = (int*)p;              p += (size_t)NCH * SPLIT * CH * 4;
    int2*     srw     = (int2*)p;             p += (size_t)E * 8;
    ushort_t* t1b     = (ushort_t*)p;         p += (size_t)N * 128 * 2;  // t1, then t2
    ushort_t* h1b     = (ushort_t*)p;         p += (size_t)N * 128 * 2;
    float*    h2      = (float*)p;            p += (size_t)N * 64 * 4;
    float*    part    = (float*)p;            p += (size_t)RB * 128 * 64 * 4;
    int*      pcnt    = (int*)p;              /* RB*128 ints */

    k_hist<<<NCH * SPLIT, 512, 0, stream>>>(src, dst, Pin, Pout, E, epb);
    k_hredscan<<<NB, 256, 0, stream>>>(Pin, Pout, cin, nin, nout, excl, bsum, N);
    k_scan2<<<1, 256, 0, stream>>>(bsum, boff, NB);
    k_scan3<<<NB, 256, 0, stream>>>(excl, boff, row_off, N);
    k_fillr<<<NCH * SPLIT, 512, 0, stream>>>(src, dst, ew, nout, Pin, row_off,
                                             srw, E, epb);

    k_gemm<128, 8, false><<<(N + 63) / 64, 256, 0, stream>>>(x, W1, t1b, N, 128);
    k_agg<128, 32, true><<<(N + 7) / 8, 256, 0, stream>>>(row_off, cin, srw, nin,
                                                          t1b, h1b, N);

    k_gemm<64, 4, true><<<(N + 63) / 64, 256, 0, stream>>>(h1b, W2, t1b, N, 128);
    k_agg<64, 16, false><<<(N + 15) / 16, 256, 0, stream>>>(row_off, cin, srw, nin,
                                                            t1b, h2, N);

    const int npb = (N + RB - 1) / RB;
    k_rpart<<<RB, 256, 0, stream>>>(h2, gid, part, pcnt, N, npb);
    k_rfinal<<<(128 * 64 + 255) / 256, 256, 0, stream>>>(part, pcnt, (float*)d_out,
                                                         128 * 64);
}